// Round 11
// baseline (442.639 us; speedup 1.0000x reference)
//
#include <hip/hip_runtime.h>

#define NN 50000
#define NPAD 50048   // rows padded to multiple of 64 for MFMA tiles
#define NE 800000
#define FIN 64
#define H 128
#define NG 16
#define POOL_BLOCKS 200
#define POOL_NODES 250
#define SCAN_BLOCKS 196  // ceil(NN/256)
#define NBUCK 98         // buckets of 512 dst nodes
#define FILLA_BLOCKS 64
#define FILLA_CHUNK (NE / FILLA_BLOCKS)  // 12500
#define CHUNK_U 16       // uints per node per feature-chunk (32 feats)
#define CSR_CAP 1200000  // >= NE + 7*NN
#define DUMMY NN         // zero pad row used for CSR padding
#define AGG_NB (NPAD / 32)  // 1564 blocks per chunk

typedef __bf16 bf16x8 __attribute__((ext_vector_type(8)));
typedef float f32x4 __attribute__((ext_vector_type(4)));

// ---- helpers ----
__device__ inline unsigned short bf16r(float x) {
    unsigned int u = __float_as_uint(x);
    return (unsigned short)((u + 0x7fffu + ((u >> 16) & 1u)) >> 16);
}
__device__ inline unsigned int pack_bf16x2(float a, float b) {
    return (unsigned int)bf16r(a) | ((unsigned int)bf16r(b) << 16);
}
__device__ inline float bf_lo(unsigned int u) { return __uint_as_float(u << 16); }
__device__ inline float bf_hi(unsigned int u) { return __uint_as_float(u & 0xffff0000u); }

// ================= CSR build =================
__global__ __launch_bounds__(256) void hist_kernel(const int* __restrict__ dst,
                                                   int* __restrict__ cnt) {
    int e = blockIdx.x * 256 + threadIdx.x;
    if (e < NE) atomicAdd(&cnt[dst[e]], 1);
}

// per-block sums of real and padded (to x8) counts
__global__ __launch_bounds__(256) void scanA_kernel(const int* __restrict__ cnt,
                                                    int* __restrict__ bsumR,
                                                    int* __restrict__ bsumP) {
    __shared__ int redR[4], redP[4];
    int i = blockIdx.x * 256 + threadIdx.x;
    int v = (i < NN) ? cnt[i] : 0;
    int p = (v + 7) & ~7;
    for (int off = 32; off > 0; off >>= 1) {
        v += __shfl_down(v, off);
        p += __shfl_down(p, off);
    }
    if ((threadIdx.x & 63) == 0) {
        redR[threadIdx.x >> 6] = v;
        redP[threadIdx.x >> 6] = p;
    }
    __syncthreads();
    if (threadIdx.x == 0) {
        bsumR[blockIdx.x] = redR[0] + redR[1] + redR[2] + redR[3];
        bsumP[blockIdx.x] = redP[0] + redP[1] + redP[2] + redP[3];
    }
}

// exclusive scan of both partial arrays
__global__ __launch_bounds__(256) void scanB_kernel(int* __restrict__ bsumR,
                                                    int* __restrict__ bsumP) {
    __shared__ int sR[256], sP[256];
    int t = threadIdx.x;
    int vR = (t < SCAN_BLOCKS) ? bsumR[t] : 0;
    int vP = (t < SCAN_BLOCKS) ? bsumP[t] : 0;
    sR[t] = vR; sP[t] = vP;
    __syncthreads();
    for (int off = 1; off < 256; off <<= 1) {
        int uR = (t >= off) ? sR[t - off] : 0;
        int uP = (t >= off) ? sP[t - off] : 0;
        __syncthreads();
        sR[t] += uR; sP[t] += uP;
        __syncthreads();
    }
    if (t < SCAN_BLOCKS) {
        bsumR[t] = sR[t] - vR;  // exclusive
        bsumP[t] = sP[t] - vP;
    }
}

// scanC: padded rowptr/cursor (rowptr extended through NPAD: pad rows empty)
// + dinv (0 on pad rows) + real bucket bases
__global__ __launch_bounds__(256) void scanC_kernel(const int* __restrict__ cnt,
                                                    const int* __restrict__ bsumR,
                                                    const int* __restrict__ bsumP,
                                                    int* __restrict__ rowptr,
                                                    int* __restrict__ cursor,
                                                    float* __restrict__ dinv,
                                                    int* __restrict__ gbase) {
    __shared__ int sR[256], sP[256];
    int t = threadIdx.x;
    int i = blockIdx.x * 256 + t;
    int v = (i < NN) ? cnt[i] : 0;
    int p = (v + 7) & ~7;
    sR[t] = v; sP[t] = p;
    __syncthreads();
    for (int off = 1; off < 256; off <<= 1) {
        int uR = (t >= off) ? sR[t - off] : 0;
        int uP = (t >= off) ? sP[t - off] : 0;
        __syncthreads();
        sR[t] += uR; sP[t] += uP;
        __syncthreads();
    }
    if (i < NN) {
        int exP = bsumP[blockIdx.x] + sP[t] - p;
        rowptr[i] = exP;
        cursor[i] = exP;
        dinv[i] = rsqrtf((float)v + 1.0f);  // +1 self-loop
        if ((i & 511) == 0) gbase[i >> 9] = bsumR[blockIdx.x] + sR[t] - v;
    } else if (i <= NPAD) {
        // only the last block reaches here; block total = bsumP + sP[255]
        int totalP = bsumP[blockIdx.x] + sP[255];
        rowptr[i] = totalP;       // pad rows: empty edge lists
        if (i < NPAD) dinv[i] = 0.0f;
    }
}

// csr pre-init: every slot points at the zero dummy row
__global__ __launch_bounds__(256) void csr_init_kernel(int* __restrict__ csr) {
    int i = blockIdx.x * 256 + threadIdx.x;
    if (i < CSR_CAP) csr[i] = DUMMY;
}

// fillA: bucket edges by dst>>9 into compact ebuf (contiguous appends)
__global__ __launch_bounds__(256) void fillA_kernel(const int* __restrict__ ei,
                                                    int* __restrict__ gbase,
                                                    unsigned int* __restrict__ ebuf) {
    __shared__ int hist[128];
    __shared__ int base[128];
    const int t = threadIdx.x;
    if (t < 128) hist[t] = 0;
    __syncthreads();
    const int e0 = blockIdx.x * FILLA_CHUNK;
    for (int e = e0 + t; e < e0 + FILLA_CHUNK; e += 256)
        atomicAdd(&hist[ei[NE + e] >> 9], 1);
    __syncthreads();
    if (t < 128) {
        int h = (t < NBUCK) ? hist[t] : 0;
        base[t] = h ? atomicAdd(&gbase[t], h) : 0;
    }
    __syncthreads();
    for (int e = e0 + t; e < e0 + FILLA_CHUNK; e += 256) {
        int d = ei[NE + e];
        int s = ei[e];
        int pos = atomicAdd(&base[d >> 9], 1);
        ebuf[pos] = (unsigned int)s | ((unsigned int)d << 16);
    }
}

// fillB: one block per bucket; after fillA, gbase[b] = real prefix end of bucket b
__global__ __launch_bounds__(256) void fillB_kernel(const unsigned int* __restrict__ ebuf,
                                                    const int* __restrict__ gbase,
                                                    int* __restrict__ cursor,
                                                    int* __restrict__ csr) {
    const int b = blockIdx.x;
    const int lo = b ? gbase[b - 1] : 0;
    const int hi = gbase[b];
    for (int i = lo + threadIdx.x; i < hi; i += 256) {
        unsigned int p = ebuf[i];
        int s = (int)(p & 0xFFFFu);
        int d = (int)(p >> 16);
        int pos = atomicAdd(&cursor[d], 1);
        csr[pos] = s;
    }
}

// ================= converts =================
// chunked layout: [chunk][node][32 shorts], chunk = feature>>5
__global__ __launch_bounds__(256) void cvt_x_kernel(const float* __restrict__ x,
                                                    unsigned short* __restrict__ xb) {
    int e = blockIdx.x * 256 + threadIdx.x;  // NPAD*64
    if (e >= NPAD * FIN) return;
    int n = e >> 6, k = e & 63;
    unsigned short v = (n < NN) ? bf16r(x[n * FIN + k]) : (unsigned short)0;
    xb[(size_t)(k >> 5) * (NPAD * 32) + n * 32 + (k & 31)] = v;
}

// all four weight transposes in one launch. Wt[n*K+k] = bf16(W[k*H+n])
__global__ __launch_bounds__(256) void cvt_w_all_kernel(const float* __restrict__ W1,
                                                        const float* __restrict__ W2,
                                                        const float* __restrict__ W3,
                                                        const float* __restrict__ W4,
                                                        unsigned short* __restrict__ Wt1,
                                                        unsigned short* __restrict__ Wt2,
                                                        unsigned short* __restrict__ Wt3,
                                                        unsigned short* __restrict__ Wt4) {
    int t = blockIdx.x * 256 + threadIdx.x;
    if (t < H * FIN) {
        int n = t / FIN, k = t % FIN;
        Wt1[t] = bf16r(W1[k * H + n]);
        return;
    }
    int u = t - H * FIN;
    const float* W = W2;
    unsigned short* Wt = Wt2;
    if (u >= 2 * H * H) { W = W4; Wt = Wt4; u -= 2 * H * H; }
    else if (u >= H * H) { W = W3; Wt = Wt3; u -= H * H; }
    if (u < H * H) {
        int n = u / H, k = u % H;
        Wt[u] = bf16r(W[k * H + n]);
    }
}

// ===== MFMA GEMM (chunked in/out): hw' = (h @ W) * dinv[row], bf16 out =====
// Epilogue goes through LDS: fp32 tile staged, then packed uint4 coalesced stores.
#define LSTRIDE 130
template <int K>
__global__ __launch_bounds__(256) void gemm_mfma_kernel(const unsigned short* __restrict__ hb,
                                                        const unsigned short* __restrict__ Wt,
                                                        const float* __restrict__ dinv,
                                                        unsigned int* __restrict__ outu) {
    __shared__ float ls[64 * LSTRIDE];  // ~33 KB
    const int wave = threadIdx.x >> 6, lane = threadIdx.x & 63;
    const int m15 = lane & 15, quad = lane >> 4;
    const int row0 = blockIdx.x * 64;
    const int arow = row0 + wave * 16 + m15;

    bf16x8 a[K / 32];
#pragma unroll
    for (int ks = 0; ks < K / 32; ks++)
        a[ks] = *(const bf16x8*)&hb[(size_t)ks * (NPAD * 32) + arow * 32 + quad * 8];

    const int lrow = wave * 16 + quad * 4;
    float dv[4];
#pragma unroll
    for (int r = 0; r < 4; r++) dv[r] = dinv[row0 + lrow + r];

#pragma unroll
    for (int ct = 0; ct < 8; ct++) {
        f32x4 acc = {0.f, 0.f, 0.f, 0.f};
#pragma unroll
        for (int ks = 0; ks < K / 32; ks++) {
            bf16x8 b = *(const bf16x8*)&Wt[(ct * 16 + m15) * K + ks * 32 + quad * 8];
            acc = __builtin_amdgcn_mfma_f32_16x16x32_bf16(a[ks], b, acc, 0, 0, 0);
        }
#pragma unroll
        for (int r = 0; r < 4; r++)
            ls[(lrow + r) * LSTRIDE + ct * 16 + m15] = acc[r] * dv[r];
    }
    __syncthreads();

    // packed coalesced stores: 1024 uint4 per block, 4 per thread
#pragma unroll
    for (int k = 0; k < 4; k++) {
        int idx = threadIdx.x + 256 * k;
        int c = idx >> 8, row = (idx >> 2) & 63, q = idx & 3;
        const float* p = &ls[row * LSTRIDE + c * 32 + q * 8];
        uint4 o;
        o.x = pack_bf16x2(p[0], p[1]);
        o.y = pack_bf16x2(p[2], p[3]);
        o.z = pack_bf16x2(p[4], p[5]);
        o.w = pack_bf16x2(p[6], p[7]);
        *(uint4*)&outu[(size_t)c * (NPAD * CHUNK_U) + (size_t)(row0 + row) * CHUNK_U + q * 4] = o;
    }
}

// ====== feature-chunked gather aggregation, TWO nodes per 16-lane group ======
// Block = 32 nodes (4 waves x 8). Group g owns nodes nA = base+g, nB = base+g+4
// and interleaves both edge walks: 4 csr int4 loads + 16 gathers in flight per
// group per iteration (2x the MLP of one-node-per-group). CSR rows padded to x8
// with DUMMY (zero hwb row) -> all loops tail-free, aligned int4 loads.
template <bool RELU_BIAS>
__global__ __launch_bounds__(256) void agg_kernel(const unsigned int* __restrict__ hwc,
                                                  const int* __restrict__ rowptr,
                                                  const int* __restrict__ csr,
                                                  const float* __restrict__ dinv,
                                                  const float* __restrict__ bias,
                                                  unsigned int* __restrict__ outc) {
    const int chunk = blockIdx.x / AGG_NB;
    const int nb = blockIdx.x % AGG_NB;
    const int wave = threadIdx.x >> 6, lane = threadIdx.x & 63;
    const int g = lane >> 4, u = lane & 15;
    const int nA = nb * 32 + wave * 8 + g;
    const int nB = nA + 4;
    const unsigned int* __restrict__ slice = hwc + (size_t)chunk * (NPAD * CHUNK_U);

    unsigned int svA = slice[nA * CHUNK_U + u];
    unsigned int svB = slice[nB * CHUNK_U + u];
    float axA = bf_lo(svA), ayA = bf_hi(svA);
    float axB = bf_lo(svB), ayB = bf_hi(svB);

    int iA = rowptr[nA];
    const int eA = rowptr[nA + 1];
    int iB = rowptr[nB];
    const int eB = rowptr[nB + 1];

    for (; iA < eA && iB < eB; iA += 8, iB += 8) {
        int4 a0 = *(const int4*)&csr[iA];
        int4 a1 = *(const int4*)&csr[iA + 4];
        int4 b0 = *(const int4*)&csr[iB];
        int4 b1 = *(const int4*)&csr[iB + 4];
        unsigned int vA0 = slice[a0.x * CHUNK_U + u], vA1 = slice[a0.y * CHUNK_U + u];
        unsigned int vA2 = slice[a0.z * CHUNK_U + u], vA3 = slice[a0.w * CHUNK_U + u];
        unsigned int vA4 = slice[a1.x * CHUNK_U + u], vA5 = slice[a1.y * CHUNK_U + u];
        unsigned int vA6 = slice[a1.z * CHUNK_U + u], vA7 = slice[a1.w * CHUNK_U + u];
        unsigned int vB0 = slice[b0.x * CHUNK_U + u], vB1 = slice[b0.y * CHUNK_U + u];
        unsigned int vB2 = slice[b0.z * CHUNK_U + u], vB3 = slice[b0.w * CHUNK_U + u];
        unsigned int vB4 = slice[b1.x * CHUNK_U + u], vB5 = slice[b1.y * CHUNK_U + u];
        unsigned int vB6 = slice[b1.z * CHUNK_U + u], vB7 = slice[b1.w * CHUNK_U + u];
        axA += bf_lo(vA0) + bf_lo(vA1) + bf_lo(vA2) + bf_lo(vA3) +
               bf_lo(vA4) + bf_lo(vA5) + bf_lo(vA6) + bf_lo(vA7);
        ayA += bf_hi(vA0) + bf_hi(vA1) + bf_hi(vA2) + bf_hi(vA3) +
               bf_hi(vA4) + bf_hi(vA5) + bf_hi(vA6) + bf_hi(vA7);
        axB += bf_lo(vB0) + bf_lo(vB1) + bf_lo(vB2) + bf_lo(vB3) +
               bf_lo(vB4) + bf_lo(vB5) + bf_lo(vB6) + bf_lo(vB7);
        ayB += bf_hi(vB0) + bf_hi(vB1) + bf_hi(vB2) + bf_hi(vB3) +
               bf_hi(vB4) + bf_hi(vB5) + bf_hi(vB6) + bf_hi(vB7);
    }
    for (; iA < eA; iA += 8) {
        int4 a0 = *(const int4*)&csr[iA];
        int4 a1 = *(const int4*)&csr[iA + 4];
        unsigned int v0 = slice[a0.x * CHUNK_U + u], v1 = slice[a0.y * CHUNK_U + u];
        unsigned int v2 = slice[a0.z * CHUNK_U + u], v3 = slice[a0.w * CHUNK_U + u];
        unsigned int v4 = slice[a1.x * CHUNK_U + u], v5 = slice[a1.y * CHUNK_U + u];
        unsigned int v6 = slice[a1.z * CHUNK_U + u], v7 = slice[a1.w * CHUNK_U + u];
        axA += bf_lo(v0) + bf_lo(v1) + bf_lo(v2) + bf_lo(v3) +
               bf_lo(v4) + bf_lo(v5) + bf_lo(v6) + bf_lo(v7);
        ayA += bf_hi(v0) + bf_hi(v1) + bf_hi(v2) + bf_hi(v3) +
               bf_hi(v4) + bf_hi(v5) + bf_hi(v6) + bf_hi(v7);
    }
    for (; iB < eB; iB += 8) {
        int4 b0 = *(const int4*)&csr[iB];
        int4 b1 = *(const int4*)&csr[iB + 4];
        unsigned int v0 = slice[b0.x * CHUNK_U + u], v1 = slice[b0.y * CHUNK_U + u];
        unsigned int v2 = slice[b0.z * CHUNK_U + u], v3 = slice[b0.w * CHUNK_U + u];
        unsigned int v4 = slice[b1.x * CHUNK_U + u], v5 = slice[b1.y * CHUNK_U + u];
        unsigned int v6 = slice[b1.z * CHUNK_U + u], v7 = slice[b1.w * CHUNK_U + u];
        axB += bf_lo(v0) + bf_lo(v1) + bf_lo(v2) + bf_lo(v3) +
               bf_lo(v4) + bf_lo(v5) + bf_lo(v6) + bf_lo(v7);
        ayB += bf_hi(v0) + bf_hi(v1) + bf_hi(v2) + bf_hi(v3) +
               bf_hi(v4) + bf_hi(v5) + bf_hi(v6) + bf_hi(v7);
    }

    float dA = dinv[nA], dB = dinv[nB];
    axA *= dA; ayA *= dA;
    axB *= dB; ayB *= dB;
    if (RELU_BIAS) {
        float2 bvA = ((const float2*)bias)[chunk * CHUNK_U + u];
        axA = fmaxf(axA + bvA.x, 0.f);
        ayA = fmaxf(ayA + bvA.y, 0.f);
        axB = fmaxf(axB + bvA.x, 0.f);
        ayB = fmaxf(ayB + bvA.y, 0.f);
    }
    unsigned int* ob = outc + (size_t)chunk * (NPAD * CHUNK_U);
    ob[nA * CHUNK_U + u] = pack_bf16x2(axA, ayA);
    ob[nB * CHUNK_U + u] = pack_bf16x2(axB, ayB);
}

// ======== pooling: block-local segment reduction (batch sorted), chunked bf16 in ========
__global__ __launch_bounds__(256) void pool_kernel(const unsigned int* __restrict__ hbu,
                                                   const float* __restrict__ b4,
                                                   const int* __restrict__ batch,
                                                   float* __restrict__ pooled,
                                                   float* __restrict__ cnt) {
    __shared__ int bs[POOL_NODES];
    const int tid = threadIdx.x;
    const int n0 = blockIdx.x * POOL_NODES;
    for (int i = tid; i < POOL_NODES; i += 256) bs[i] = batch[n0 + i];
    __syncthreads();
    const int c2 = tid & 63;                 // feature-uint index 0..63
    const int chunk = c2 >> 4, u = c2 & 15;
    const int rsub = tid >> 6;  // 0..3
    float2 bb = ((const float2*)b4)[c2];
    float2 acc = {0.f, 0.f};
    float cacc = 0.f;
    int curg = bs[rsub];
    const size_t coff = (size_t)chunk * (NPAD * CHUNK_U) + u;
    for (int r = rsub; r < POOL_NODES; r += 4) {
        int g = bs[r];
        if (g != curg) {
            atomicAdd(&pooled[curg * H + c2 * 2], acc.x);
            atomicAdd(&pooled[curg * H + c2 * 2 + 1], acc.y);
            if (c2 == 0) atomicAdd(&cnt[curg], cacc);
            acc.x = acc.y = 0.f;
            cacc = 0.f;
            curg = g;
        }
        unsigned int v = hbu[coff + (size_t)(n0 + r) * CHUNK_U];
        acc.x += bf_lo(v) + bb.x;
        acc.y += bf_hi(v) + bb.y;
        cacc += 1.f;
    }
    atomicAdd(&pooled[curg * H + c2 * 2], acc.x);
    atomicAdd(&pooled[curg * H + c2 * 2 + 1], acc.y);
    if (c2 == 0) atomicAdd(&cnt[curg], cacc);
}

// ================= final MLP (single block) =================
__global__ __launch_bounds__(1024) void mlp_kernel(const float* __restrict__ pooled,
                                                   const float* __restrict__ cnt,
                                                   const float* __restrict__ lw1,
                                                   const float* __restrict__ lb1,
                                                   const float* __restrict__ lw2,
                                                   const float* __restrict__ lb2,
                                                   float* __restrict__ out) {
    __shared__ float mean_s[NG * H];
    __shared__ float hid_s[NG * 64];
    int tid = threadIdx.x;
    for (int i = tid; i < NG * H; i += 1024) {
        int g = i >> 7;
        mean_s[i] = pooled[i] / fmaxf(cnt[g], 1.0f);
    }
    __syncthreads();
    {
        int g = tid >> 6, j = tid & 63;
        float acc = lb1[j];
        for (int f = 0; f < H; f++) acc += mean_s[g * H + f] * lw1[f * 64 + j];
        hid_s[g * 64 + j] = fmaxf(acc, 0.f);
    }
    __syncthreads();
    if (tid < 32) {
        int g = tid >> 1, c = tid & 1;
        float acc = lb2[c];
        for (int j = 0; j < 64; j++) acc += hid_s[g * 64 + j] * lw2[j * 2 + c];
        out[g * 2 + c] = acc;
    }
}

extern "C" void kernel_launch(void* const* d_in, const int* in_sizes, int n_in,
                              void* d_out, int out_size, void* d_ws, size_t ws_size,
                              hipStream_t stream) {
    const float* x = (const float*)d_in[0];
    const int* ei = (const int*)d_in[1];
    const int* batch = (const int*)d_in[2];
    const float* W1 = (const float*)d_in[3];
    const float* b1 = (const float*)d_in[4];
    const float* W2 = (const float*)d_in[5];
    const float* b2 = (const float*)d_in[6];
    const float* W3 = (const float*)d_in[7];
    const float* b3 = (const float*)d_in[8];
    const float* W4 = (const float*)d_in[9];
    const float* b4 = (const float*)d_in[10];
    const float* lw1 = (const float*)d_in[11];
    const float* lb1 = (const float*)d_in[12];
    const float* lw2 = (const float*)d_in[13];
    const float* lb2 = (const float*)d_in[14];
    float* out = (float*)d_out;

    // workspace layout (4-byte units); total ~41 MB
    int* wsi = (int*)d_ws;
    int* cnt = wsi;                                        // 50048
    int* bsumR = wsi + 50048;                              // 256
    int* bsumP = wsi + 50304;                              // 256
    int* rowptr = wsi + 50560;                             // 50064 (need NPAD+1)
    int* cursor = wsi + 100624;                            // 50048
    int* csr = wsi + 150672;                               // CSR_CAP
    float* dinv = (float*)(wsi + 1350672);                 // 50048
    unsigned short* Wt1 = (unsigned short*)(wsi + 1400720);  // 128*64
    unsigned short* Wt2 = (unsigned short*)(wsi + 1404816);  // 128*128
    unsigned short* Wt3 = (unsigned short*)(wsi + 1413008);
    unsigned short* Wt4 = (unsigned short*)(wsi + 1421200);
    unsigned short* xb = (unsigned short*)(wsi + 1429392);   // NPAD*64 (chunked)
    unsigned int* hb = (unsigned int*)(wsi + 3030928);       // NPAD*64 (chunked bf16x2)
    unsigned int* hwb = (unsigned int*)(wsi + 6234000);      // NPAD*64 (chunked bf16x2)
    float* pooled = (float*)(wsi + 9437072);                 // NG*H + NG
    float* pcnt = pooled + NG * H;
    int* gbase = wsi + 9439200;                              // 128
    unsigned int* ebuf = (unsigned int*)(wsi + 9439328);     // NE

    const int edgeBlocks = (NE + 255) / 256;   // 3125
    const int gemmBlocks = NPAD / 64;          // 782
    const int aggBlocks = 4 * AGG_NB;          // 6256, chunk-major

    // ---- CSR build (once; reused by all 4 layers) ----
    hipMemsetAsync(cnt, 0, NN * sizeof(int), stream);
    hist_kernel<<<edgeBlocks, 256, 0, stream>>>(ei + NE, cnt);
    scanA_kernel<<<SCAN_BLOCKS, 256, 0, stream>>>(cnt, bsumR, bsumP);
    scanB_kernel<<<1, 256, 0, stream>>>(bsumR, bsumP);
    scanC_kernel<<<SCAN_BLOCKS, 256, 0, stream>>>(cnt, bsumR, bsumP, rowptr, cursor, dinv, gbase);
    csr_init_kernel<<<(CSR_CAP + 255) / 256, 256, 0, stream>>>(csr);
    fillA_kernel<<<FILLA_BLOCKS, 256, 0, stream>>>(ei, gbase, ebuf);
    fillB_kernel<<<NBUCK, 256, 0, stream>>>(ebuf, gbase, cursor, csr);

    // ---- converts ----
    cvt_x_kernel<<<(NPAD * FIN) / 256, 256, 0, stream>>>(x, xb);
    cvt_w_all_kernel<<<(H * FIN + 3 * H * H) / 256, 256, 0, stream>>>(
        W1, W2, W3, W4, Wt1, Wt2, Wt3, Wt4);

    // ---- layer 1 ----
    gemm_mfma_kernel<FIN><<<gemmBlocks, 256, 0, stream>>>(xb, Wt1, dinv, hwb);
    agg_kernel<true><<<aggBlocks, 256, 0, stream>>>(hwb, rowptr, csr, dinv, b1, hb);
    // ---- layer 2 ----
    gemm_mfma_kernel<H><<<gemmBlocks, 256, 0, stream>>>((unsigned short*)hb, Wt2, dinv, hwb);
    agg_kernel<true><<<aggBlocks, 256, 0, stream>>>(hwb, rowptr, csr, dinv, b2, hb);
    // ---- layer 3 ----
    gemm_mfma_kernel<H><<<gemmBlocks, 256, 0, stream>>>((unsigned short*)hb, Wt3, dinv, hwb);
    agg_kernel<true><<<aggBlocks, 256, 0, stream>>>(hwb, rowptr, csr, dinv, b3, hb);
    // ---- layer 4 (no relu/bias; b4 fused in pool) ----
    gemm_mfma_kernel<H><<<gemmBlocks, 256, 0, stream>>>((unsigned short*)hb, Wt4, dinv, hwb);
    agg_kernel<false><<<aggBlocks, 256, 0, stream>>>(hwb, rowptr, csr, dinv, nullptr, hb);

    // ---- pooling (fused +b4) + MLP ----
    hipMemsetAsync(pooled, 0, (NG * H + NG) * sizeof(float), stream);
    pool_kernel<<<POOL_BLOCKS, 256, 0, stream>>>(hb, b4, batch, pooled, pcnt);
    mlp_kernel<<<1, 1024, 0, stream>>>(pooled, pcnt, lw1, lb1, lw2, lb2, out);
}

// Round 12
// 432.882 us; speedup vs baseline: 1.0225x; 1.0225x over previous
//
#include <hip/hip_runtime.h>

#define NN 50000
#define NPAD 50048   // rows padded to multiple of 64 for MFMA tiles
#define NE 800000
#define FIN 64
#define H 128
#define NG 16
#define POOL_BLOCKS 200
#define POOL_NODES 250
#define SCAN_BLOCKS 196  // ceil(NN/256)
#define NBUCK 98         // buckets of 512 dst nodes
#define FILLA_BLOCKS 64
#define FILLA_CHUNK (NE / FILLA_BLOCKS)  // 12500
#define CHUNK_U 16       // uints per node per feature-chunk (32 feats)
#define CSR_CAP 1200000  // ushort entries; >= NE + 7*NN
#define DUMMY NN         // zero pad row used for CSR padding
#define AGG_CH (NN / 16) // 3125 blocks per chunk

typedef __bf16 bf16x8 __attribute__((ext_vector_type(8)));
typedef float f32x4 __attribute__((ext_vector_type(4)));

// ---- helpers ----
__device__ inline unsigned short bf16r(float x) {
    unsigned int u = __float_as_uint(x);
    return (unsigned short)((u + 0x7fffu + ((u >> 16) & 1u)) >> 16);
}
__device__ inline unsigned int pack_bf16x2(float a, float b) {
    return (unsigned int)bf16r(a) | ((unsigned int)bf16r(b) << 16);
}
__device__ inline float bf_lo(unsigned int u) { return __uint_as_float(u << 16); }
__device__ inline float bf_hi(unsigned int u) { return __uint_as_float(u & 0xffff0000u); }

// ================= CSR build =================
__global__ __launch_bounds__(256) void hist_kernel(const int* __restrict__ dst,
                                                   int* __restrict__ cnt) {
    int e = blockIdx.x * 256 + threadIdx.x;
    if (e < NE) atomicAdd(&cnt[dst[e]], 1);
}

// per-block sums of real and padded (to x8) counts
__global__ __launch_bounds__(256) void scanA_kernel(const int* __restrict__ cnt,
                                                    int* __restrict__ bsumR,
                                                    int* __restrict__ bsumP) {
    __shared__ int redR[4], redP[4];
    int i = blockIdx.x * 256 + threadIdx.x;
    int v = (i < NN) ? cnt[i] : 0;
    int p = (v + 7) & ~7;
    for (int off = 32; off > 0; off >>= 1) {
        v += __shfl_down(v, off);
        p += __shfl_down(p, off);
    }
    if ((threadIdx.x & 63) == 0) {
        redR[threadIdx.x >> 6] = v;
        redP[threadIdx.x >> 6] = p;
    }
    __syncthreads();
    if (threadIdx.x == 0) {
        bsumR[blockIdx.x] = redR[0] + redR[1] + redR[2] + redR[3];
        bsumP[blockIdx.x] = redP[0] + redP[1] + redP[2] + redP[3];
    }
}

// exclusive scan of both partial arrays
__global__ __launch_bounds__(256) void scanB_kernel(int* __restrict__ bsumR,
                                                    int* __restrict__ bsumP) {
    __shared__ int sR[256], sP[256];
    int t = threadIdx.x;
    int vR = (t < SCAN_BLOCKS) ? bsumR[t] : 0;
    int vP = (t < SCAN_BLOCKS) ? bsumP[t] : 0;
    sR[t] = vR; sP[t] = vP;
    __syncthreads();
    for (int off = 1; off < 256; off <<= 1) {
        int uR = (t >= off) ? sR[t - off] : 0;
        int uP = (t >= off) ? sP[t - off] : 0;
        __syncthreads();
        sR[t] += uR; sP[t] += uP;
        __syncthreads();
    }
    if (t < SCAN_BLOCKS) {
        bsumR[t] = sR[t] - vR;  // exclusive
        bsumP[t] = sP[t] - vP;
    }
}

// scanC: padded rowptr/cursor + dinv (0 on pad rows) + real bucket bases
__global__ __launch_bounds__(256) void scanC_kernel(const int* __restrict__ cnt,
                                                    const int* __restrict__ bsumR,
                                                    const int* __restrict__ bsumP,
                                                    int* __restrict__ rowptr,
                                                    int* __restrict__ cursor,
                                                    float* __restrict__ dinv,
                                                    int* __restrict__ gbase) {
    __shared__ int sR[256], sP[256];
    int t = threadIdx.x;
    int i = blockIdx.x * 256 + t;
    int v = (i < NN) ? cnt[i] : 0;
    int p = (v + 7) & ~7;
    sR[t] = v; sP[t] = p;
    __syncthreads();
    for (int off = 1; off < 256; off <<= 1) {
        int uR = (t >= off) ? sR[t - off] : 0;
        int uP = (t >= off) ? sP[t - off] : 0;
        __syncthreads();
        sR[t] += uR; sP[t] += uP;
        __syncthreads();
    }
    if (i < NN) {
        int exP = bsumP[blockIdx.x] + sP[t] - p;
        rowptr[i] = exP;
        cursor[i] = exP;
        dinv[i] = rsqrtf((float)v + 1.0f);  // +1 self-loop
        if ((i & 511) == 0) gbase[i >> 9] = bsumR[blockIdx.x] + sR[t] - v;
    } else if (i <= NPAD) {
        int totalP = bsumP[blockIdx.x] + sP[255];
        rowptr[i] = totalP;
        if (i < NPAD) dinv[i] = 0.0f;
    }
}

// csr pre-init: every ushort slot -> DUMMY (pairs packed in uint stores)
__global__ __launch_bounds__(256) void csr_init_kernel(unsigned int* __restrict__ csr2) {
    int i = blockIdx.x * 256 + threadIdx.x;
    const unsigned int dd = (unsigned int)DUMMY | ((unsigned int)DUMMY << 16);
    if (i < CSR_CAP / 2) csr2[i] = dd;
}

// fillA: bucket edges by dst>>9 into compact ebuf (contiguous appends)
__global__ __launch_bounds__(256) void fillA_kernel(const int* __restrict__ ei,
                                                    int* __restrict__ gbase,
                                                    unsigned int* __restrict__ ebuf) {
    __shared__ int hist[128];
    __shared__ int base[128];
    const int t = threadIdx.x;
    if (t < 128) hist[t] = 0;
    __syncthreads();
    const int e0 = blockIdx.x * FILLA_CHUNK;
    for (int e = e0 + t; e < e0 + FILLA_CHUNK; e += 256)
        atomicAdd(&hist[ei[NE + e] >> 9], 1);
    __syncthreads();
    if (t < 128) {
        int h = (t < NBUCK) ? hist[t] : 0;
        base[t] = h ? atomicAdd(&gbase[t], h) : 0;
    }
    __syncthreads();
    for (int e = e0 + t; e < e0 + FILLA_CHUNK; e += 256) {
        int d = ei[NE + e];
        int s = ei[e];
        int pos = atomicAdd(&base[d >> 9], 1);
        ebuf[pos] = (unsigned int)s | ((unsigned int)d << 16);
    }
}

// fillB: one block per bucket; scatter ushort src within the bucket's csr window
__global__ __launch_bounds__(256) void fillB_kernel(const unsigned int* __restrict__ ebuf,
                                                    const int* __restrict__ gbase,
                                                    int* __restrict__ cursor,
                                                    unsigned short* __restrict__ csr) {
    const int b = blockIdx.x;
    const int lo = b ? gbase[b - 1] : 0;
    const int hi = gbase[b];
    for (int i = lo + threadIdx.x; i < hi; i += 256) {
        unsigned int p = ebuf[i];
        int s = (int)(p & 0xFFFFu);
        int d = (int)(p >> 16);
        int pos = atomicAdd(&cursor[d], 1);
        csr[pos] = (unsigned short)s;
    }
}

// ================= converts =================
// chunked layout: [chunk][node][32 shorts], chunk = feature>>5
__global__ __launch_bounds__(256) void cvt_x_kernel(const float* __restrict__ x,
                                                    unsigned short* __restrict__ xb) {
    int e = blockIdx.x * 256 + threadIdx.x;  // NPAD*64
    if (e >= NPAD * FIN) return;
    int n = e >> 6, k = e & 63;
    unsigned short v = (n < NN) ? bf16r(x[n * FIN + k]) : (unsigned short)0;
    xb[(size_t)(k >> 5) * (NPAD * 32) + n * 32 + (k & 31)] = v;
}

// all four weight transposes in one launch. Wt[n*K+k] = bf16(W[k*H+n])
__global__ __launch_bounds__(256) void cvt_w_all_kernel(const float* __restrict__ W1,
                                                        const float* __restrict__ W2,
                                                        const float* __restrict__ W3,
                                                        const float* __restrict__ W4,
                                                        unsigned short* __restrict__ Wt1,
                                                        unsigned short* __restrict__ Wt2,
                                                        unsigned short* __restrict__ Wt3,
                                                        unsigned short* __restrict__ Wt4) {
    int t = blockIdx.x * 256 + threadIdx.x;
    if (t < H * FIN) {
        int n = t / FIN, k = t % FIN;
        Wt1[t] = bf16r(W1[k * H + n]);
        return;
    }
    int u = t - H * FIN;
    const float* W = W2;
    unsigned short* Wt = Wt2;
    if (u >= 2 * H * H) { W = W4; Wt = Wt4; u -= 2 * H * H; }
    else if (u >= H * H) { W = W3; Wt = Wt3; u -= H * H; }
    if (u < H * H) {
        int n = u / H, k = u % H;
        Wt[u] = bf16r(W[k * H + n]);
    }
}

// ===== MFMA GEMM (chunked in/out): hw' = (h @ W) * dinv[row], bf16 out =====
// Epilogue goes through LDS: fp32 tile staged, then packed uint4 coalesced stores.
#define LSTRIDE 130
template <int K>
__global__ __launch_bounds__(256) void gemm_mfma_kernel(const unsigned short* __restrict__ hb,
                                                        const unsigned short* __restrict__ Wt,
                                                        const float* __restrict__ dinv,
                                                        unsigned int* __restrict__ outu) {
    __shared__ float ls[64 * LSTRIDE];  // ~33 KB
    const int wave = threadIdx.x >> 6, lane = threadIdx.x & 63;
    const int m15 = lane & 15, quad = lane >> 4;
    const int row0 = blockIdx.x * 64;
    const int arow = row0 + wave * 16 + m15;

    bf16x8 a[K / 32];
#pragma unroll
    for (int ks = 0; ks < K / 32; ks++)
        a[ks] = *(const bf16x8*)&hb[(size_t)ks * (NPAD * 32) + arow * 32 + quad * 8];

    const int lrow = wave * 16 + quad * 4;
    float dv[4];
#pragma unroll
    for (int r = 0; r < 4; r++) dv[r] = dinv[row0 + lrow + r];

#pragma unroll
    for (int ct = 0; ct < 8; ct++) {
        f32x4 acc = {0.f, 0.f, 0.f, 0.f};
#pragma unroll
        for (int ks = 0; ks < K / 32; ks++) {
            bf16x8 b = *(const bf16x8*)&Wt[(ct * 16 + m15) * K + ks * 32 + quad * 8];
            acc = __builtin_amdgcn_mfma_f32_16x16x32_bf16(a[ks], b, acc, 0, 0, 0);
        }
#pragma unroll
        for (int r = 0; r < 4; r++)
            ls[(lrow + r) * LSTRIDE + ct * 16 + m15] = acc[r] * dv[r];
    }
    __syncthreads();

    // packed coalesced stores: 1024 uint4 per block, 4 per thread
#pragma unroll
    for (int k = 0; k < 4; k++) {
        int idx = threadIdx.x + 256 * k;
        int c = idx >> 8, row = (idx >> 2) & 63, q = idx & 3;
        const float* p = &ls[row * LSTRIDE + c * 32 + q * 8];
        uint4 o;
        o.x = pack_bf16x2(p[0], p[1]);
        o.y = pack_bf16x2(p[2], p[3]);
        o.z = pack_bf16x2(p[4], p[5]);
        o.w = pack_bf16x2(p[6], p[7]);
        *(uint4*)&outu[(size_t)c * (NPAD * CHUNK_U) + (size_t)(row0 + row) * CHUNK_U + q * 4] = o;
    }
}

// ====== feature-chunked gather aggregation, one node per 16-lane group ======
// Block = 16 nodes (4 waves x 4). ushort CSR rows padded to x8 with DUMMY
// (hwb pad row is exactly 0 since gemm writes *dinv=0) -> tail-free loop:
// one uint4 load = 8 edge indices, then 8 x 64B gathers in flight per group.
template <bool RELU_BIAS>
__global__ __launch_bounds__(256) void agg_kernel(const unsigned int* __restrict__ hwc,
                                                  const int* __restrict__ rowptr,
                                                  const unsigned short* __restrict__ csr,
                                                  const float* __restrict__ dinv,
                                                  const float* __restrict__ bias,
                                                  unsigned int* __restrict__ outc) {
    const int chunk = blockIdx.x / AGG_CH;
    const int nb = blockIdx.x % AGG_CH;
    const int wave = threadIdx.x >> 6, lane = threadIdx.x & 63;
    const int g = lane >> 4, u = lane & 15;
    const int n = nb * 16 + wave * 4 + g;
    const unsigned int* __restrict__ slice = hwc + (size_t)chunk * (NPAD * CHUNK_U);

    unsigned int sv = slice[n * CHUNK_U + u];  // self-loop term
    float ax = bf_lo(sv), ay = bf_hi(sv);

    const int beg = rowptr[n], end = rowptr[n + 1];  // multiples of 8
    for (int i = beg; i < end; i += 8) {
        uint4 c = *(const uint4*)&csr[i];  // 8 ushort srcs
        int s0 = c.x & 0xFFFF, s1 = c.x >> 16;
        int s2 = c.y & 0xFFFF, s3 = c.y >> 16;
        int s4 = c.z & 0xFFFF, s5 = c.z >> 16;
        int s6 = c.w & 0xFFFF, s7 = c.w >> 16;
        unsigned int v0 = slice[s0 * CHUNK_U + u], v1 = slice[s1 * CHUNK_U + u];
        unsigned int v2 = slice[s2 * CHUNK_U + u], v3 = slice[s3 * CHUNK_U + u];
        unsigned int v4 = slice[s4 * CHUNK_U + u], v5 = slice[s5 * CHUNK_U + u];
        unsigned int v6 = slice[s6 * CHUNK_U + u], v7 = slice[s7 * CHUNK_U + u];
        ax += bf_lo(v0) + bf_lo(v1) + bf_lo(v2) + bf_lo(v3) +
              bf_lo(v4) + bf_lo(v5) + bf_lo(v6) + bf_lo(v7);
        ay += bf_hi(v0) + bf_hi(v1) + bf_hi(v2) + bf_hi(v3) +
              bf_hi(v4) + bf_hi(v5) + bf_hi(v6) + bf_hi(v7);
    }

    float d = dinv[n];
    ax *= d;
    ay *= d;
    if (RELU_BIAS) {
        float2 bv = ((const float2*)bias)[chunk * CHUNK_U + u];
        ax = fmaxf(ax + bv.x, 0.f);
        ay = fmaxf(ay + bv.y, 0.f);
    }
    outc[(size_t)chunk * (NPAD * CHUNK_U) + n * CHUNK_U + u] = pack_bf16x2(ax, ay);
}

// ======== pooling: block-local segment reduction (batch sorted), chunked bf16 in ========
__global__ __launch_bounds__(256) void pool_kernel(const unsigned int* __restrict__ hbu,
                                                   const float* __restrict__ b4,
                                                   const int* __restrict__ batch,
                                                   float* __restrict__ pooled,
                                                   float* __restrict__ cnt) {
    __shared__ int bs[POOL_NODES];
    const int tid = threadIdx.x;
    const int n0 = blockIdx.x * POOL_NODES;
    for (int i = tid; i < POOL_NODES; i += 256) bs[i] = batch[n0 + i];
    __syncthreads();
    const int c2 = tid & 63;                 // feature-uint index 0..63
    const int chunk = c2 >> 4, u = c2 & 15;
    const int rsub = tid >> 6;  // 0..3
    float2 bb = ((const float2*)b4)[c2];
    float2 acc = {0.f, 0.f};
    float cacc = 0.f;
    int curg = bs[rsub];
    const size_t coff = (size_t)chunk * (NPAD * CHUNK_U) + u;
    for (int r = rsub; r < POOL_NODES; r += 4) {
        int g = bs[r];
        if (g != curg) {
            atomicAdd(&pooled[curg * H + c2 * 2], acc.x);
            atomicAdd(&pooled[curg * H + c2 * 2 + 1], acc.y);
            if (c2 == 0) atomicAdd(&cnt[curg], cacc);
            acc.x = acc.y = 0.f;
            cacc = 0.f;
            curg = g;
        }
        unsigned int v = hbu[coff + (size_t)(n0 + r) * CHUNK_U];
        acc.x += bf_lo(v) + bb.x;
        acc.y += bf_hi(v) + bb.y;
        cacc += 1.f;
    }
    atomicAdd(&pooled[curg * H + c2 * 2], acc.x);
    atomicAdd(&pooled[curg * H + c2 * 2 + 1], acc.y);
    if (c2 == 0) atomicAdd(&cnt[curg], cacc);
}

// ================= final MLP (single block) =================
__global__ __launch_bounds__(1024) void mlp_kernel(const float* __restrict__ pooled,
                                                   const float* __restrict__ cnt,
                                                   const float* __restrict__ lw1,
                                                   const float* __restrict__ lb1,
                                                   const float* __restrict__ lw2,
                                                   const float* __restrict__ lb2,
                                                   float* __restrict__ out) {
    __shared__ float mean_s[NG * H];
    __shared__ float hid_s[NG * 64];
    int tid = threadIdx.x;
    for (int i = tid; i < NG * H; i += 1024) {
        int g = i >> 7;
        mean_s[i] = pooled[i] / fmaxf(cnt[g], 1.0f);
    }
    __syncthreads();
    {
        int g = tid >> 6, j = tid & 63;
        float acc = lb1[j];
        for (int f = 0; f < H; f++) acc += mean_s[g * H + f] * lw1[f * 64 + j];
        hid_s[g * 64 + j] = fmaxf(acc, 0.f);
    }
    __syncthreads();
    if (tid < 32) {
        int g = tid >> 1, c = tid & 1;
        float acc = lb2[c];
        for (int j = 0; j < 64; j++) acc += hid_s[g * 64 + j] * lw2[j * 2 + c];
        out[g * 2 + c] = acc;
    }
}

extern "C" void kernel_launch(void* const* d_in, const int* in_sizes, int n_in,
                              void* d_out, int out_size, void* d_ws, size_t ws_size,
                              hipStream_t stream) {
    const float* x = (const float*)d_in[0];
    const int* ei = (const int*)d_in[1];
    const int* batch = (const int*)d_in[2];
    const float* W1 = (const float*)d_in[3];
    const float* b1 = (const float*)d_in[4];
    const float* W2 = (const float*)d_in[5];
    const float* b2 = (const float*)d_in[6];
    const float* W3 = (const float*)d_in[7];
    const float* b3 = (const float*)d_in[8];
    const float* W4 = (const float*)d_in[9];
    const float* b4 = (const float*)d_in[10];
    const float* lw1 = (const float*)d_in[11];
    const float* lb1 = (const float*)d_in[12];
    const float* lw2 = (const float*)d_in[13];
    const float* lb2 = (const float*)d_in[14];
    float* out = (float*)d_out;

    // workspace layout (4-byte units)
    int* wsi = (int*)d_ws;
    int* cnt = wsi;                                        // 50048
    int* bsumR = wsi + 50048;                              // 256
    int* bsumP = wsi + 50304;                              // 256
    int* rowptr = wsi + 50560;                             // 50064 (NPAD+1)
    int* cursor = wsi + 100624;                            // 50048
    unsigned short* csr = (unsigned short*)(wsi + 150672); // CSR_CAP ushorts (600K uints)
    float* dinv = (float*)(wsi + 1350672);                 // 50048
    unsigned short* Wt1 = (unsigned short*)(wsi + 1400720);  // 128*64
    unsigned short* Wt2 = (unsigned short*)(wsi + 1404816);  // 128*128
    unsigned short* Wt3 = (unsigned short*)(wsi + 1413008);
    unsigned short* Wt4 = (unsigned short*)(wsi + 1421200);
    unsigned short* xb = (unsigned short*)(wsi + 1429392);   // NPAD*64 (chunked)
    unsigned int* hb = (unsigned int*)(wsi + 3030928);       // NPAD*64 (chunked bf16x2)
    unsigned int* hwb = (unsigned int*)(wsi + 6234000);      // NPAD*64 (chunked bf16x2)
    float* pooled = (float*)(wsi + 9437072);                 // NG*H + NG
    float* pcnt = pooled + NG * H;
    int* gbase = wsi + 9439200;                              // 128
    unsigned int* ebuf = (unsigned int*)(wsi + 9439328);     // NE

    const int edgeBlocks = (NE + 255) / 256;   // 3125
    const int gemmBlocks = NPAD / 64;          // 782
    const int aggBlocks = 4 * AGG_CH;          // 12500, chunk-major

    // ---- CSR build (once; reused by all 4 layers) ----
    hipMemsetAsync(cnt, 0, NN * sizeof(int), stream);
    hist_kernel<<<edgeBlocks, 256, 0, stream>>>(ei + NE, cnt);
    scanA_kernel<<<SCAN_BLOCKS, 256, 0, stream>>>(cnt, bsumR, bsumP);
    scanB_kernel<<<1, 256, 0, stream>>>(bsumR, bsumP);
    scanC_kernel<<<SCAN_BLOCKS, 256, 0, stream>>>(cnt, bsumR, bsumP, rowptr, cursor, dinv, gbase);
    csr_init_kernel<<<(CSR_CAP / 2 + 255) / 256, 256, 0, stream>>>((unsigned int*)csr);
    fillA_kernel<<<FILLA_BLOCKS, 256, 0, stream>>>(ei, gbase, ebuf);
    fillB_kernel<<<NBUCK, 256, 0, stream>>>(ebuf, gbase, cursor, csr);

    // ---- converts ----
    cvt_x_kernel<<<(NPAD * FIN) / 256, 256, 0, stream>>>(x, xb);
    cvt_w_all_kernel<<<(H * FIN + 3 * H * H) / 256, 256, 0, stream>>>(
        W1, W2, W3, W4, Wt1, Wt2, Wt3, Wt4);

    // ---- layer 1 ----
    gemm_mfma_kernel<FIN><<<gemmBlocks, 256, 0, stream>>>(xb, Wt1, dinv, hwb);
    agg_kernel<true><<<aggBlocks, 256, 0, stream>>>(hwb, rowptr, csr, dinv, b1, hb);
    // ---- layer 2 ----
    gemm_mfma_kernel<H><<<gemmBlocks, 256, 0, stream>>>((unsigned short*)hb, Wt2, dinv, hwb);
    agg_kernel<true><<<aggBlocks, 256, 0, stream>>>(hwb, rowptr, csr, dinv, b2, hb);
    // ---- layer 3 ----
    gemm_mfma_kernel<H><<<gemmBlocks, 256, 0, stream>>>((unsigned short*)hb, Wt3, dinv, hwb);
    agg_kernel<true><<<aggBlocks, 256, 0, stream>>>(hwb, rowptr, csr, dinv, b3, hb);
    // ---- layer 4 (no relu/bias; b4 fused in pool) ----
    gemm_mfma_kernel<H><<<gemmBlocks, 256, 0, stream>>>((unsigned short*)hb, Wt4, dinv, hwb);
    agg_kernel<false><<<aggBlocks, 256, 0, stream>>>(hwb, rowptr, csr, dinv, nullptr, hb);

    // ---- pooling (fused +b4) + MLP ----
    hipMemsetAsync(pooled, 0, (NG * H + NG) * sizeof(float), stream);
    pool_kernel<<<POOL_BLOCKS, 256, 0, stream>>>(hb, b4, batch, pooled, pcnt);
    mlp_kernel<<<1, 1024, 0, stream>>>(pooled, pcnt, lw1, lb1, lw2, lb2, out);
}

// Round 14
// 388.748 us; speedup vs baseline: 1.1386x; 1.1135x over previous
//
#include <hip/hip_runtime.h>

#define NN 50000
#define NPAD 50048   // rows padded to multiple of 64 for MFMA tiles
#define NE 800000
#define FIN 64
#define H 128
#define NG 16
#define POOL_BLOCKS 200
#define POOL_NODES 250
#define NBUCK 98         // buckets of 512 dst nodes
#define BUCK_CAP 10000   // edges per bucket capacity (expected 8192 +- 90)
#define FILLA_BLOCKS 64
#define FILLA_CHUNK (NE / FILLA_BLOCKS)  // 12500
#define CHUNK_U 16       // uints per node per feature-chunk (32 feats)
#define CSR_CAP 1200000  // ushort entries; >= NE + 7*NN
#define DUMMY NN         // zero pad row used for CSR padding
#define AGG_CH (NN / 16) // 3125 blocks per chunk

typedef __bf16 bf16x8 __attribute__((ext_vector_type(8)));
typedef float f32x4 __attribute__((ext_vector_type(4)));

// ---- helpers ----
__device__ inline unsigned short bf16r(float x) {
    unsigned int u = __float_as_uint(x);
    return (unsigned short)((u + 0x7fffu + ((u >> 16) & 1u)) >> 16);
}
__device__ inline unsigned int pack_bf16x2(float a, float b) {
    return (unsigned int)bf16r(a) | ((unsigned int)bf16r(b) << 16);
}
__device__ inline float bf_lo(unsigned int u) { return __uint_as_float(u << 16); }
__device__ inline float bf_hi(unsigned int u) { return __uint_as_float(u & 0xffff0000u); }

// ================= CSR build (bucket-local, 4 kernels + 1 tiny memset) =================
// fillA: bucket edges by dst>>9 into fixed-capacity bucket windows of ebuf.
__global__ __launch_bounds__(256) void fillA_kernel(const int* __restrict__ ei,
                                                    int* __restrict__ gcount,
                                                    unsigned int* __restrict__ ebuf) {
    __shared__ int hist[128];
    __shared__ int base[128];
    const int t = threadIdx.x;
    if (t < 128) hist[t] = 0;
    __syncthreads();
    const int e0 = blockIdx.x * FILLA_CHUNK;
    for (int e = e0 + t; e < e0 + FILLA_CHUNK; e += 256)
        atomicAdd(&hist[ei[NE + e] >> 9], 1);
    __syncthreads();
    if (t < 128) {
        int h = (t < NBUCK) ? hist[t] : 0;
        base[t] = h ? atomicAdd(&gcount[t], h) : 0;
    }
    __syncthreads();
    for (int e = e0 + t; e < e0 + FILLA_CHUNK; e += 256) {
        int d = ei[NE + e];
        int s = ei[e];
        int b = d >> 9;
        int pos = atomicAdd(&base[b], 1);
        ebuf[b * BUCK_CAP + pos] = (unsigned int)s | ((unsigned int)d << 16);
    }
}

// fillB1: per bucket: LDS histogram of its edges -> per-node cnt + padded total
__global__ __launch_bounds__(256) void fillB1_kernel(const unsigned int* __restrict__ ebuf,
                                                     const int* __restrict__ gcount,
                                                     int* __restrict__ cnt,
                                                     int* __restrict__ gptot) {
    __shared__ int lh[512];
    __shared__ int red[4];
    const int b = blockIdx.x, t = threadIdx.x;
    lh[t] = 0;
    lh[t + 256] = 0;
    __syncthreads();
    const int ne = gcount[b];
    const unsigned int* __restrict__ eb = ebuf + b * BUCK_CAP;
    const int n0 = b * 512;
    for (int i = t; i < ne; i += 256)
        atomicAdd(&lh[(int)(eb[i] >> 16) - n0], 1);
    __syncthreads();
    int c0 = lh[2 * t], c1 = lh[2 * t + 1];
    *(int2*)&cnt[n0 + 2 * t] = make_int2(c0, c1);
    int p = ((c0 + 7) & ~7) + ((c1 + 7) & ~7);
    for (int off = 32; off > 0; off >>= 1) p += __shfl_down(p, off);
    if ((t & 63) == 0) red[t >> 6] = p;
    __syncthreads();
    if (t == 0) gptot[b] = red[0] + red[1] + red[2] + red[3];
}

// scan98: exclusive scan of the 98 padded bucket totals; also zero pooled+pcnt
__global__ __launch_bounds__(256) void scan98_kernel(const int* __restrict__ gptot,
                                                     int* __restrict__ gpbase,
                                                     float* __restrict__ pooled) {
    __shared__ int s[128];
    const int t = threadIdx.x;
    int v = 0;
    if (t < 128) {
        v = (t < NBUCK) ? gptot[t] : 0;
        s[t] = v;
    }
    __syncthreads();
    for (int off = 1; off < 128; off <<= 1) {
        int u = 0;
        if (t < 128 && t >= off) u = s[t - off];
        __syncthreads();
        if (t < 128) s[t] += u;
        __syncthreads();
    }
    if (t < 128) gpbase[t] = s[t] - v;  // exclusive
    for (int i = t; i < NG * H + NG; i += 256) pooled[i] = 0.f;
}

// fillB2: per bucket: LDS scan -> rowptr/dinv; LDS-cursor scatter of ushort
// srcs into the bucket's csr window; DUMMY pads written in place.
__global__ __launch_bounds__(256) void fillB2_kernel(const unsigned int* __restrict__ ebuf,
                                                     const int* __restrict__ gcount,
                                                     const int* __restrict__ cnt,
                                                     const int* __restrict__ gpbase,
                                                     int* __restrict__ rowptr,
                                                     float* __restrict__ dinv,
                                                     unsigned short* __restrict__ csr) {
    __shared__ int lsum[256];
    __shared__ int loff[512];
    __shared__ int lcnt[512];
    __shared__ int lcur[512];
    const int b = blockIdx.x, t = threadIdx.x;
    const int n0 = b * 512;
    int2 c2 = *(const int2*)&cnt[n0 + 2 * t];
    int c0 = c2.x, c1 = c2.y;
    lcnt[2 * t] = c0;
    lcnt[2 * t + 1] = c1;
    int p0 = (c0 + 7) & ~7, p1 = (c1 + 7) & ~7;
    lsum[t] = p0 + p1;
    __syncthreads();
    for (int off = 1; off < 256; off <<= 1) {
        int u = (t >= off) ? lsum[t - off] : 0;
        __syncthreads();
        lsum[t] += u;
        __syncthreads();
    }
    int excl = (t == 0) ? 0 : lsum[t - 1];
    loff[2 * t] = excl;
    loff[2 * t + 1] = excl + p0;
    const int base = gpbase[b];
#pragma unroll
    for (int j2 = 0; j2 < 2; j2++) {
        int j = 2 * t + j2;
        int n = n0 + j;
        int st = base + loff[j];
        if (n < NN) {
            rowptr[n] = st;
            dinv[n] = rsqrtf((float)lcnt[j] + 1.0f);  // +1 self-loop
        } else if (n <= NPAD) {
            rowptr[n] = st;  // pad rows: empty lists (cnt 0)
            if (n < NPAD) dinv[n] = 0.0f;
        }
        lcur[j] = st;
    }
    __syncthreads();
    const int ne = gcount[b];
    const unsigned int* __restrict__ eb = ebuf + b * BUCK_CAP;
    for (int i = t; i < ne; i += 256) {
        unsigned int u = eb[i];
        int s = (int)(u & 0xFFFFu);
        int j = (int)(u >> 16) - n0;
        int pos = atomicAdd(&lcur[j], 1);
        csr[pos] = (unsigned short)s;
    }
    __syncthreads();
#pragma unroll
    for (int j2 = 0; j2 < 2; j2++) {
        int j = 2 * t + j2;
        int st = base + loff[j] + lcnt[j];
        int en = base + loff[j] + ((lcnt[j] + 7) & ~7);
        for (int k = st; k < en; k++) csr[k] = (unsigned short)DUMMY;
    }
}

// ================= prep: x convert (chunked) + all 4 weight transposes =================
__global__ __launch_bounds__(256) void prep_kernel(const float* __restrict__ x,
                                                   const float* __restrict__ W1,
                                                   const float* __restrict__ W2,
                                                   const float* __restrict__ W3,
                                                   const float* __restrict__ W4,
                                                   unsigned short* __restrict__ xb,
                                                   unsigned short* __restrict__ Wt1,
                                                   unsigned short* __restrict__ Wt2,
                                                   unsigned short* __restrict__ Wt3,
                                                   unsigned short* __restrict__ Wt4) {
    int e = blockIdx.x * 256 + threadIdx.x;
    if (e < NPAD * FIN) {
        int n = e >> 6, k = e & 63;
        unsigned short v = (n < NN) ? bf16r(x[n * FIN + k]) : (unsigned short)0;
        xb[(size_t)(k >> 5) * (NPAD * 32) + n * 32 + (k & 31)] = v;
        return;
    }
    int t = e - NPAD * FIN;
    if (t < H * FIN) {
        int n = t / FIN, k = t % FIN;
        Wt1[t] = bf16r(W1[k * H + n]);
        return;
    }
    int u = t - H * FIN;
    const float* W = W2;
    unsigned short* Wt = Wt2;
    if (u >= 2 * H * H) { W = W4; Wt = Wt4; u -= 2 * H * H; }
    else if (u >= H * H) { W = W3; Wt = Wt3; u -= H * H; }
    if (u < H * H) {
        int n = u / H, k = u % H;
        Wt[u] = bf16r(W[k * H + n]);
    }
}

// ===== MFMA GEMM (chunked in/out): hw' = (h @ W) * dinv[row], bf16 out =====
#define LSTRIDE 130
template <int K>
__global__ __launch_bounds__(256) void gemm_mfma_kernel(const unsigned short* __restrict__ hb,
                                                        const unsigned short* __restrict__ Wt,
                                                        const float* __restrict__ dinv,
                                                        unsigned int* __restrict__ outu) {
    __shared__ float ls[64 * LSTRIDE];  // ~33 KB
    const int wave = threadIdx.x >> 6, lane = threadIdx.x & 63;
    const int m15 = lane & 15, quad = lane >> 4;
    const int row0 = blockIdx.x * 64;
    const int arow = row0 + wave * 16 + m15;

    bf16x8 a[K / 32];
#pragma unroll
    for (int ks = 0; ks < K / 32; ks++)
        a[ks] = *(const bf16x8*)&hb[(size_t)ks * (NPAD * 32) + arow * 32 + quad * 8];

    const int lrow = wave * 16 + quad * 4;
    float dv[4];
#pragma unroll
    for (int r = 0; r < 4; r++) dv[r] = dinv[row0 + lrow + r];

#pragma unroll
    for (int ct = 0; ct < 8; ct++) {
        f32x4 acc = {0.f, 0.f, 0.f, 0.f};
#pragma unroll
        for (int ks = 0; ks < K / 32; ks++) {
            bf16x8 b = *(const bf16x8*)&Wt[(ct * 16 + m15) * K + ks * 32 + quad * 8];
            acc = __builtin_amdgcn_mfma_f32_16x16x32_bf16(a[ks], b, acc, 0, 0, 0);
        }
#pragma unroll
        for (int r = 0; r < 4; r++)
            ls[(lrow + r) * LSTRIDE + ct * 16 + m15] = acc[r] * dv[r];
    }
    __syncthreads();

#pragma unroll
    for (int k = 0; k < 4; k++) {
        int idx = threadIdx.x + 256 * k;
        int c = idx >> 8, row = (idx >> 2) & 63, q = idx & 3;
        const float* p = &ls[row * LSTRIDE + c * 32 + q * 8];
        uint4 o;
        o.x = pack_bf16x2(p[0], p[1]);
        o.y = pack_bf16x2(p[2], p[3]);
        o.z = pack_bf16x2(p[4], p[5]);
        o.w = pack_bf16x2(p[6], p[7]);
        *(uint4*)&outu[(size_t)c * (NPAD * CHUNK_U) + (size_t)(row0 + row) * CHUNK_U + q * 4] = o;
    }
}

// ====== feature-chunked gather aggregation, one node per 16-lane group ======
template <bool RELU_BIAS>
__global__ __launch_bounds__(256) void agg_kernel(const unsigned int* __restrict__ hwc,
                                                  const int* __restrict__ rowptr,
                                                  const unsigned short* __restrict__ csr,
                                                  const float* __restrict__ dinv,
                                                  const float* __restrict__ bias,
                                                  unsigned int* __restrict__ outc) {
    const int chunk = blockIdx.x / AGG_CH;
    const int nb = blockIdx.x % AGG_CH;
    const int wave = threadIdx.x >> 6, lane = threadIdx.x & 63;
    const int g = lane >> 4, u = lane & 15;
    const int n = nb * 16 + wave * 4 + g;
    const unsigned int* __restrict__ slice = hwc + (size_t)chunk * (NPAD * CHUNK_U);

    unsigned int sv = slice[n * CHUNK_U + u];  // self-loop term
    float ax = bf_lo(sv), ay = bf_hi(sv);

    const int beg = rowptr[n], end = rowptr[n + 1];  // multiples of 8
    for (int i = beg; i < end; i += 8) {
        uint4 c = *(const uint4*)&csr[i];  // 8 ushort srcs
        int s0 = c.x & 0xFFFF, s1 = c.x >> 16;
        int s2 = c.y & 0xFFFF, s3 = c.y >> 16;
        int s4 = c.z & 0xFFFF, s5 = c.z >> 16;
        int s6 = c.w & 0xFFFF, s7 = c.w >> 16;
        unsigned int v0 = slice[s0 * CHUNK_U + u], v1 = slice[s1 * CHUNK_U + u];
        unsigned int v2 = slice[s2 * CHUNK_U + u], v3 = slice[s3 * CHUNK_U + u];
        unsigned int v4 = slice[s4 * CHUNK_U + u], v5 = slice[s5 * CHUNK_U + u];
        unsigned int v6 = slice[s6 * CHUNK_U + u], v7 = slice[s7 * CHUNK_U + u];
        ax += bf_lo(v0) + bf_lo(v1) + bf_lo(v2) + bf_lo(v3) +
              bf_lo(v4) + bf_lo(v5) + bf_lo(v6) + bf_lo(v7);
        ay += bf_hi(v0) + bf_hi(v1) + bf_hi(v2) + bf_hi(v3) +
              bf_hi(v4) + bf_hi(v5) + bf_hi(v6) + bf_hi(v7);
    }

    float d = dinv[n];
    ax *= d;
    ay *= d;
    if (RELU_BIAS) {
        float2 bv = ((const float2*)bias)[chunk * CHUNK_U + u];
        ax = fmaxf(ax + bv.x, 0.f);
        ay = fmaxf(ay + bv.y, 0.f);
    }
    outc[(size_t)chunk * (NPAD * CHUNK_U) + n * CHUNK_U + u] = pack_bf16x2(ax, ay);
}

// ======== pooling: block-local segment reduction (batch sorted), chunked bf16 in ========
__global__ __launch_bounds__(256) void pool_kernel(const unsigned int* __restrict__ hbu,
                                                   const float* __restrict__ b4,
                                                   const int* __restrict__ batch,
                                                   float* __restrict__ pooled,
                                                   float* __restrict__ cnt) {
    __shared__ int bs[POOL_NODES];
    const int tid = threadIdx.x;
    const int n0 = blockIdx.x * POOL_NODES;
    for (int i = tid; i < POOL_NODES; i += 256) bs[i] = batch[n0 + i];
    __syncthreads();
    const int c2 = tid & 63;                 // feature-uint index 0..63
    const int chunk = c2 >> 4, u = c2 & 15;
    const int rsub = tid >> 6;  // 0..3
    float2 bb = ((const float2*)b4)[c2];
    float2 acc = {0.f, 0.f};
    float cacc = 0.f;
    int curg = bs[rsub];
    const size_t coff = (size_t)chunk * (NPAD * CHUNK_U) + u;
    for (int r = rsub; r < POOL_NODES; r += 4) {
        int g = bs[r];
        if (g != curg) {
            atomicAdd(&pooled[curg * H + c2 * 2], acc.x);
            atomicAdd(&pooled[curg * H + c2 * 2 + 1], acc.y);
            if (c2 == 0) atomicAdd(&cnt[curg], cacc);
            acc.x = acc.y = 0.f;
            cacc = 0.f;
            curg = g;
        }
        unsigned int v = hbu[coff + (size_t)(n0 + r) * CHUNK_U];
        acc.x += bf_lo(v) + bb.x;
        acc.y += bf_hi(v) + bb.y;
        cacc += 1.f;
    }
    atomicAdd(&pooled[curg * H + c2 * 2], acc.x);
    atomicAdd(&pooled[curg * H + c2 * 2 + 1], acc.y);
    if (c2 == 0) atomicAdd(&cnt[curg], cacc);
}

// ================= final MLP (single block) =================
__global__ __launch_bounds__(1024) void mlp_kernel(const float* __restrict__ pooled,
                                                   const float* __restrict__ cnt,
                                                   const float* __restrict__ lw1,
                                                   const float* __restrict__ lb1,
                                                   const float* __restrict__ lw2,
                                                   const float* __restrict__ lb2,
                                                   float* __restrict__ out) {
    __shared__ float mean_s[NG * H];
    __shared__ float hid_s[NG * 64];
    int tid = threadIdx.x;
    for (int i = tid; i < NG * H; i += 1024) {
        int g = i >> 7;
        mean_s[i] = pooled[i] / fmaxf(cnt[g], 1.0f);
    }
    __syncthreads();
    {
        int g = tid >> 6, j = tid & 63;
        float acc = lb1[j];
        for (int f = 0; f < H; f++) acc += mean_s[g * H + f] * lw1[f * 64 + j];
        hid_s[g * 64 + j] = fmaxf(acc, 0.f);
    }
    __syncthreads();
    if (tid < 32) {
        int g = tid >> 1, c = tid & 1;
        float acc = lb2[c];
        for (int j = 0; j < 64; j++) acc += hid_s[g * 64 + j] * lw2[j * 2 + c];
        out[g * 2 + c] = acc;
    }
}

extern "C" void kernel_launch(void* const* d_in, const int* in_sizes, int n_in,
                              void* d_out, int out_size, void* d_ws, size_t ws_size,
                              hipStream_t stream) {
    const float* x = (const float*)d_in[0];
    const int* ei = (const int*)d_in[1];
    const int* batch = (const int*)d_in[2];
    const float* W1 = (const float*)d_in[3];
    const float* b1 = (const float*)d_in[4];
    const float* W2 = (const float*)d_in[5];
    const float* b2 = (const float*)d_in[6];
    const float* W3 = (const float*)d_in[7];
    const float* b3 = (const float*)d_in[8];
    const float* W4 = (const float*)d_in[9];
    const float* b4 = (const float*)d_in[10];
    const float* lw1 = (const float*)d_in[11];
    const float* lb1 = (const float*)d_in[12];
    const float* lw2 = (const float*)d_in[13];
    const float* lb2 = (const float*)d_in[14];
    float* out = (float*)d_out;

    // workspace layout (4-byte units; sizes annotated in ints); ~39 MB
    int* wsi = (int*)d_ws;
    int* gcount = wsi;                                      // @0        128
    int* gptot = wsi + 128;                                 // @128      128
    int* gpbase = wsi + 256;                                // @256      256
    int* cnt = wsi + 512;                                   // @512      50176
    int* rowptr = wsi + 50688;                              // @50688    50064 (NPAD+1)
    unsigned short* csr = (unsigned short*)(wsi + 100752);  // @100752   600000 (1.2M ushorts)
    float* dinv = (float*)(wsi + 700752);                   // @700752   50048
    unsigned short* Wt1 = (unsigned short*)(wsi + 750800);  // @750800   4096 (8192 shorts)
    unsigned short* Wt2 = (unsigned short*)(wsi + 754896);  // @754896   8192 (16384 shorts)
    unsigned short* Wt3 = (unsigned short*)(wsi + 763088);  // @763088   8192
    unsigned short* Wt4 = (unsigned short*)(wsi + 771280);  // @771280   8192
    unsigned short* xb = (unsigned short*)(wsi + 779472);   // @779472   1601536 (NPAD*64 shorts)
    unsigned int* hb = (unsigned int*)(wsi + 2381008);      // @2381008  3203072 (NPAD*64 uints)
    unsigned int* hwb = (unsigned int*)(wsi + 5584080);     // @5584080  3203072
    float* pooled = (float*)(wsi + 8787152);                // @8787152  2064 (NG*H+NG)
    float* pcnt = pooled + NG * H;
    unsigned int* ebuf = (unsigned int*)(wsi + 8789216);    // @8789216  980000 -> ends 9769216

    const int gemmBlocks = NPAD / 64;          // 782
    const int aggBlocks = 4 * AGG_CH;          // 12500, chunk-major
    const int prepBlocks = (NPAD * FIN + H * FIN + 3 * H * H + 255) / 256;

    // ---- CSR build (bucket-local; reused by all 4 layers) ----
    hipMemsetAsync(gcount, 0, NBUCK * sizeof(int), stream);
    fillA_kernel<<<FILLA_BLOCKS, 256, 0, stream>>>(ei, gcount, ebuf);
    fillB1_kernel<<<NBUCK, 256, 0, stream>>>(ebuf, gcount, cnt, gptot);
    scan98_kernel<<<1, 256, 0, stream>>>(gptot, gpbase, pooled);
    fillB2_kernel<<<NBUCK, 256, 0, stream>>>(ebuf, gcount, cnt, gpbase, rowptr, dinv, csr);

    // ---- input/weight converts (one launch) ----
    prep_kernel<<<prepBlocks, 256, 0, stream>>>(x, W1, W2, W3, W4, xb, Wt1, Wt2, Wt3, Wt4);

    // ---- layer 1 ----
    gemm_mfma_kernel<FIN><<<gemmBlocks, 256, 0, stream>>>(xb, Wt1, dinv, hwb);
    agg_kernel<true><<<aggBlocks, 256, 0, stream>>>(hwb, rowptr, csr, dinv, b1, hb);
    // ---- layer 2 ----
    gemm_mfma_kernel<H><<<gemmBlocks, 256, 0, stream>>>((unsigned short*)hb, Wt2, dinv, hwb);
    agg_kernel<true><<<aggBlocks, 256, 0, stream>>>(hwb, rowptr, csr, dinv, b2, hb);
    // ---- layer 3 ----
    gemm_mfma_kernel<H><<<gemmBlocks, 256, 0, stream>>>((unsigned short*)hb, Wt3, dinv, hwb);
    agg_kernel<true><<<aggBlocks, 256, 0, stream>>>(hwb, rowptr, csr, dinv, b3, hb);
    // ---- layer 4 (no relu/bias; b4 fused in pool) ----
    gemm_mfma_kernel<H><<<gemmBlocks, 256, 0, stream>>>((unsigned short*)hb, Wt4, dinv, hwb);
    agg_kernel<false><<<aggBlocks, 256, 0, stream>>>(hwb, rowptr, csr, dinv, nullptr, hb);

    // ---- pooling (fused +b4, pooled zeroed in scan98) + MLP ----
    pool_kernel<<<POOL_BLOCKS, 256, 0, stream>>>(hb, b4, batch, pooled, pcnt);
    mlp_kernel<<<1, 1024, 0, stream>>>(pooled, pcnt, lw1, lb1, lw2, lb2, out);
}

// Round 15
// 375.262 us; speedup vs baseline: 1.1795x; 1.0359x over previous
//
#include <hip/hip_runtime.h>

#define NN 50000
#define NPAD 50048   // rows padded to multiple of 64 for MFMA tiles
#define NE 800000
#define FIN 64
#define H 128
#define NG 16
#define POOL_BLOCKS 200
#define POOL_NODES 250
#define NBUCK 98         // buckets of 512 dst nodes
#define BUCK_CAP 10000   // edges per bucket capacity (expected 8163 +- 90)
#define FILLA_BLOCKS 512
#define FILLA_CHUNK 1563  // ceil(NE / FILLA_BLOCKS)
#define CHUNK_U 16       // uints per node per feature-chunk (32 feats)
#define CSR_CAP 1200000  // ushort entries; >= NE + 7*NN
#define DUMMY NN         // zero pad row used for CSR padding
#define AGG_CH (NN / 16) // 3125 blocks per chunk

typedef __bf16 bf16x8 __attribute__((ext_vector_type(8)));
typedef float f32x4 __attribute__((ext_vector_type(4)));

// ---- helpers ----
__device__ inline unsigned short bf16r(float x) {
    unsigned int u = __float_as_uint(x);
    return (unsigned short)((u + 0x7fffu + ((u >> 16) & 1u)) >> 16);
}
__device__ inline unsigned int pack_bf16x2(float a, float b) {
    return (unsigned int)bf16r(a) | ((unsigned int)bf16r(b) << 16);
}
__device__ inline float bf_lo(unsigned int u) { return __uint_as_float(u << 16); }
__device__ inline float bf_hi(unsigned int u) { return __uint_as_float(u & 0xffff0000u); }

// ================= CSR build (bucket-local, 4 kernels + 1 tiny memset) =================
// fillA: bucket edges by dst>>9 into fixed-capacity bucket windows of ebuf.
// 512 blocks (vs 64 in r14): occupancy was the bottleneck (2.4% -> ~19%).
__global__ __launch_bounds__(256) void fillA_kernel(const int* __restrict__ ei,
                                                    int* __restrict__ gcount,
                                                    unsigned int* __restrict__ ebuf) {
    __shared__ int hist[128];
    __shared__ int base[128];
    const int t = threadIdx.x;
    if (t < 128) hist[t] = 0;
    __syncthreads();
    const int e0 = blockIdx.x * FILLA_CHUNK;
    const int e1 = min(e0 + FILLA_CHUNK, NE);
    for (int e = e0 + t; e < e1; e += 256)
        atomicAdd(&hist[ei[NE + e] >> 9], 1);
    __syncthreads();
    if (t < 128) {
        int h = (t < NBUCK) ? hist[t] : 0;
        base[t] = h ? atomicAdd(&gcount[t], h) : 0;
    }
    __syncthreads();
    for (int e = e0 + t; e < e1; e += 256) {
        int d = ei[NE + e];
        int s = ei[e];
        int b = d >> 9;
        int pos = atomicAdd(&base[b], 1);
        ebuf[b * BUCK_CAP + pos] = (unsigned int)s | ((unsigned int)d << 16);
    }
}

// fillB1: per bucket: LDS histogram of its edges -> per-node cnt + padded total
__global__ __launch_bounds__(256) void fillB1_kernel(const unsigned int* __restrict__ ebuf,
                                                     const int* __restrict__ gcount,
                                                     int* __restrict__ cnt,
                                                     int* __restrict__ gptot) {
    __shared__ int lh[512];
    __shared__ int red[4];
    const int b = blockIdx.x, t = threadIdx.x;
    lh[t] = 0;
    lh[t + 256] = 0;
    __syncthreads();
    const int ne = gcount[b];
    const unsigned int* __restrict__ eb = ebuf + b * BUCK_CAP;
    const int n0 = b * 512;
    for (int i = t; i < ne; i += 256)
        atomicAdd(&lh[(int)(eb[i] >> 16) - n0], 1);
    __syncthreads();
    int c0 = lh[2 * t], c1 = lh[2 * t + 1];
    *(int2*)&cnt[n0 + 2 * t] = make_int2(c0, c1);
    int p = ((c0 + 7) & ~7) + ((c1 + 7) & ~7);
    for (int off = 32; off > 0; off >>= 1) p += __shfl_down(p, off);
    if ((t & 63) == 0) red[t >> 6] = p;
    __syncthreads();
    if (t == 0) gptot[b] = red[0] + red[1] + red[2] + red[3];
}

// scan98: exclusive scan of the 98 padded bucket totals; also zero pooled+pcnt
__global__ __launch_bounds__(256) void scan98_kernel(const int* __restrict__ gptot,
                                                     int* __restrict__ gpbase,
                                                     float* __restrict__ pooled) {
    __shared__ int s[128];
    const int t = threadIdx.x;
    int v = 0;
    if (t < 128) {
        v = (t < NBUCK) ? gptot[t] : 0;
        s[t] = v;
    }
    __syncthreads();
    for (int off = 1; off < 128; off <<= 1) {
        int u = 0;
        if (t < 128 && t >= off) u = s[t - off];
        __syncthreads();
        if (t < 128) s[t] += u;
        __syncthreads();
    }
    if (t < 128) gpbase[t] = s[t] - v;  // exclusive
    for (int i = t; i < NG * H + NG; i += 256) pooled[i] = 0.f;
}

// fillB2: per bucket: LDS scan -> rowptr/dinv; LDS-cursor scatter of ushort
// srcs into the bucket's csr window; DUMMY pads written in place.
__global__ __launch_bounds__(256) void fillB2_kernel(const unsigned int* __restrict__ ebuf,
                                                     const int* __restrict__ gcount,
                                                     const int* __restrict__ cnt,
                                                     const int* __restrict__ gpbase,
                                                     int* __restrict__ rowptr,
                                                     float* __restrict__ dinv,
                                                     unsigned short* __restrict__ csr) {
    __shared__ int lsum[256];
    __shared__ int loff[512];
    __shared__ int lcnt[512];
    __shared__ int lcur[512];
    const int b = blockIdx.x, t = threadIdx.x;
    const int n0 = b * 512;
    int2 c2 = *(const int2*)&cnt[n0 + 2 * t];
    int c0 = c2.x, c1 = c2.y;
    lcnt[2 * t] = c0;
    lcnt[2 * t + 1] = c1;
    int p0 = (c0 + 7) & ~7, p1 = (c1 + 7) & ~7;
    lsum[t] = p0 + p1;
    __syncthreads();
    for (int off = 1; off < 256; off <<= 1) {
        int u = (t >= off) ? lsum[t - off] : 0;
        __syncthreads();
        lsum[t] += u;
        __syncthreads();
    }
    int excl = (t == 0) ? 0 : lsum[t - 1];
    loff[2 * t] = excl;
    loff[2 * t + 1] = excl + p0;
    const int base = gpbase[b];
#pragma unroll
    for (int j2 = 0; j2 < 2; j2++) {
        int j = 2 * t + j2;
        int n = n0 + j;
        int st = base + loff[j];
        if (n < NN) {
            rowptr[n] = st;
            dinv[n] = rsqrtf((float)lcnt[j] + 1.0f);  // +1 self-loop
        } else if (n <= NPAD) {
            rowptr[n] = st;  // pad rows: empty lists (cnt 0)
            if (n < NPAD) dinv[n] = 0.0f;
        }
        lcur[j] = st;
    }
    __syncthreads();
    const int ne = gcount[b];
    const unsigned int* __restrict__ eb = ebuf + b * BUCK_CAP;
    for (int i = t; i < ne; i += 256) {
        unsigned int u = eb[i];
        int s = (int)(u & 0xFFFFu);
        int j = (int)(u >> 16) - n0;
        int pos = atomicAdd(&lcur[j], 1);
        csr[pos] = (unsigned short)s;
    }
    __syncthreads();
#pragma unroll
    for (int j2 = 0; j2 < 2; j2++) {
        int j = 2 * t + j2;
        int st = base + loff[j] + lcnt[j];
        int en = base + loff[j] + ((lcnt[j] + 7) & ~7);
        for (int k = st; k < en; k++) csr[k] = (unsigned short)DUMMY;
    }
}

// ================= prep: x convert (chunked) + all 4 weight transposes =================
__global__ __launch_bounds__(256) void prep_kernel(const float* __restrict__ x,
                                                   const float* __restrict__ W1,
                                                   const float* __restrict__ W2,
                                                   const float* __restrict__ W3,
                                                   const float* __restrict__ W4,
                                                   unsigned short* __restrict__ xb,
                                                   unsigned short* __restrict__ Wt1,
                                                   unsigned short* __restrict__ Wt2,
                                                   unsigned short* __restrict__ Wt3,
                                                   unsigned short* __restrict__ Wt4) {
    int e = blockIdx.x * 256 + threadIdx.x;
    if (e < NPAD * FIN) {
        int n = e >> 6, k = e & 63;
        unsigned short v = (n < NN) ? bf16r(x[n * FIN + k]) : (unsigned short)0;
        xb[(size_t)(k >> 5) * (NPAD * 32) + n * 32 + (k & 31)] = v;
        return;
    }
    int t = e - NPAD * FIN;
    if (t < H * FIN) {
        int n = t / FIN, k = t % FIN;
        Wt1[t] = bf16r(W1[k * H + n]);
        return;
    }
    int u = t - H * FIN;
    const float* W = W2;
    unsigned short* Wt = Wt2;
    if (u >= 2 * H * H) { W = W4; Wt = Wt4; u -= 2 * H * H; }
    else if (u >= H * H) { W = W3; Wt = Wt3; u -= H * H; }
    if (u < H * H) {
        int n = u / H, k = u % H;
        Wt[u] = bf16r(W[k * H + n]);
    }
}

// ===== MFMA GEMM (chunked in/out): hw' = (h @ W) * dinv[row], bf16 out =====
#define LSTRIDE 130
template <int K>
__global__ __launch_bounds__(256) void gemm_mfma_kernel(const unsigned short* __restrict__ hb,
                                                        const unsigned short* __restrict__ Wt,
                                                        const float* __restrict__ dinv,
                                                        unsigned int* __restrict__ outu) {
    __shared__ float ls[64 * LSTRIDE];  // ~33 KB
    const int wave = threadIdx.x >> 6, lane = threadIdx.x & 63;
    const int m15 = lane & 15, quad = lane >> 4;
    const int row0 = blockIdx.x * 64;
    const int arow = row0 + wave * 16 + m15;

    bf16x8 a[K / 32];
#pragma unroll
    for (int ks = 0; ks < K / 32; ks++)
        a[ks] = *(const bf16x8*)&hb[(size_t)ks * (NPAD * 32) + arow * 32 + quad * 8];

    const int lrow = wave * 16 + quad * 4;
    float dv[4];
#pragma unroll
    for (int r = 0; r < 4; r++) dv[r] = dinv[row0 + lrow + r];

#pragma unroll
    for (int ct = 0; ct < 8; ct++) {
        f32x4 acc = {0.f, 0.f, 0.f, 0.f};
#pragma unroll
        for (int ks = 0; ks < K / 32; ks++) {
            bf16x8 b = *(const bf16x8*)&Wt[(ct * 16 + m15) * K + ks * 32 + quad * 8];
            acc = __builtin_amdgcn_mfma_f32_16x16x32_bf16(a[ks], b, acc, 0, 0, 0);
        }
#pragma unroll
        for (int r = 0; r < 4; r++)
            ls[(lrow + r) * LSTRIDE + ct * 16 + m15] = acc[r] * dv[r];
    }
    __syncthreads();

#pragma unroll
    for (int k = 0; k < 4; k++) {
        int idx = threadIdx.x + 256 * k;
        int c = idx >> 8, row = (idx >> 2) & 63, q = idx & 3;
        const float* p = &ls[row * LSTRIDE + c * 32 + q * 8];
        uint4 o;
        o.x = pack_bf16x2(p[0], p[1]);
        o.y = pack_bf16x2(p[2], p[3]);
        o.z = pack_bf16x2(p[4], p[5]);
        o.w = pack_bf16x2(p[6], p[7]);
        *(uint4*)&outu[(size_t)c * (NPAD * CHUNK_U) + (size_t)(row0 + row) * CHUNK_U + q * 4] = o;
    }
}

// ====== feature-chunked gather aggregation, one node per 16-lane group ======
template <bool RELU_BIAS>
__global__ __launch_bounds__(256) void agg_kernel(const unsigned int* __restrict__ hwc,
                                                  const int* __restrict__ rowptr,
                                                  const unsigned short* __restrict__ csr,
                                                  const float* __restrict__ dinv,
                                                  const float* __restrict__ bias,
                                                  unsigned int* __restrict__ outc) {
    const int chunk = blockIdx.x / AGG_CH;
    const int nb = blockIdx.x % AGG_CH;
    const int wave = threadIdx.x >> 6, lane = threadIdx.x & 63;
    const int g = lane >> 4, u = lane & 15;
    const int n = nb * 16 + wave * 4 + g;
    const unsigned int* __restrict__ slice = hwc + (size_t)chunk * (NPAD * CHUNK_U);

    unsigned int sv = slice[n * CHUNK_U + u];  // self-loop term
    float ax = bf_lo(sv), ay = bf_hi(sv);

    const int beg = rowptr[n], end = rowptr[n + 1];  // multiples of 8
    for (int i = beg; i < end; i += 8) {
        uint4 c = *(const uint4*)&csr[i];  // 8 ushort srcs
        int s0 = c.x & 0xFFFF, s1 = c.x >> 16;
        int s2 = c.y & 0xFFFF, s3 = c.y >> 16;
        int s4 = c.z & 0xFFFF, s5 = c.z >> 16;
        int s6 = c.w & 0xFFFF, s7 = c.w >> 16;
        unsigned int v0 = slice[s0 * CHUNK_U + u], v1 = slice[s1 * CHUNK_U + u];
        unsigned int v2 = slice[s2 * CHUNK_U + u], v3 = slice[s3 * CHUNK_U + u];
        unsigned int v4 = slice[s4 * CHUNK_U + u], v5 = slice[s5 * CHUNK_U + u];
        unsigned int v6 = slice[s6 * CHUNK_U + u], v7 = slice[s7 * CHUNK_U + u];
        ax += bf_lo(v0) + bf_lo(v1) + bf_lo(v2) + bf_lo(v3) +
              bf_lo(v4) + bf_lo(v5) + bf_lo(v6) + bf_lo(v7);
        ay += bf_hi(v0) + bf_hi(v1) + bf_hi(v2) + bf_hi(v3) +
              bf_hi(v4) + bf_hi(v5) + bf_hi(v6) + bf_hi(v7);
    }

    float d = dinv[n];
    ax *= d;
    ay *= d;
    if (RELU_BIAS) {
        float2 bv = ((const float2*)bias)[chunk * CHUNK_U + u];
        ax = fmaxf(ax + bv.x, 0.f);
        ay = fmaxf(ay + bv.y, 0.f);
    }
    outc[(size_t)chunk * (NPAD * CHUNK_U) + n * CHUNK_U + u] = pack_bf16x2(ax, ay);
}

// ======== pooling: block-local segment reduction (batch sorted), chunked bf16 in ========
__global__ __launch_bounds__(256) void pool_kernel(const unsigned int* __restrict__ hbu,
                                                   const float* __restrict__ b4,
                                                   const int* __restrict__ batch,
                                                   float* __restrict__ pooled,
                                                   float* __restrict__ cnt) {
    __shared__ int bs[POOL_NODES];
    const int tid = threadIdx.x;
    const int n0 = blockIdx.x * POOL_NODES;
    for (int i = tid; i < POOL_NODES; i += 256) bs[i] = batch[n0 + i];
    __syncthreads();
    const int c2 = tid & 63;                 // feature-uint index 0..63
    const int chunk = c2 >> 4, u = c2 & 15;
    const int rsub = tid >> 6;  // 0..3
    float2 bb = ((const float2*)b4)[c2];
    float2 acc = {0.f, 0.f};
    float cacc = 0.f;
    int curg = bs[rsub];
    const size_t coff = (size_t)chunk * (NPAD * CHUNK_U) + u;
    for (int r = rsub; r < POOL_NODES; r += 4) {
        int g = bs[r];
        if (g != curg) {
            atomicAdd(&pooled[curg * H + c2 * 2], acc.x);
            atomicAdd(&pooled[curg * H + c2 * 2 + 1], acc.y);
            if (c2 == 0) atomicAdd(&cnt[curg], cacc);
            acc.x = acc.y = 0.f;
            cacc = 0.f;
            curg = g;
        }
        unsigned int v = hbu[coff + (size_t)(n0 + r) * CHUNK_U];
        acc.x += bf_lo(v) + bb.x;
        acc.y += bf_hi(v) + bb.y;
        cacc += 1.f;
    }
    atomicAdd(&pooled[curg * H + c2 * 2], acc.x);
    atomicAdd(&pooled[curg * H + c2 * 2 + 1], acc.y);
    if (c2 == 0) atomicAdd(&cnt[curg], cacc);
}

// ================= final MLP (single block) =================
__global__ __launch_bounds__(1024) void mlp_kernel(const float* __restrict__ pooled,
                                                   const float* __restrict__ cnt,
                                                   const float* __restrict__ lw1,
                                                   const float* __restrict__ lb1,
                                                   const float* __restrict__ lw2,
                                                   const float* __restrict__ lb2,
                                                   float* __restrict__ out) {
    __shared__ float mean_s[NG * H];
    __shared__ float hid_s[NG * 64];
    int tid = threadIdx.x;
    for (int i = tid; i < NG * H; i += 1024) {
        int g = i >> 7;
        mean_s[i] = pooled[i] / fmaxf(cnt[g], 1.0f);
    }
    __syncthreads();
    {
        int g = tid >> 6, j = tid & 63;
        float acc = lb1[j];
        for (int f = 0; f < H; f++) acc += mean_s[g * H + f] * lw1[f * 64 + j];
        hid_s[g * 64 + j] = fmaxf(acc, 0.f);
    }
    __syncthreads();
    if (tid < 32) {
        int g = tid >> 1, c = tid & 1;
        float acc = lb2[c];
        for (int j = 0; j < 64; j++) acc += hid_s[g * 64 + j] * lw2[j * 2 + c];
        out[g * 2 + c] = acc;
    }
}

extern "C" void kernel_launch(void* const* d_in, const int* in_sizes, int n_in,
                              void* d_out, int out_size, void* d_ws, size_t ws_size,
                              hipStream_t stream) {
    const float* x = (const float*)d_in[0];
    const int* ei = (const int*)d_in[1];
    const int* batch = (const int*)d_in[2];
    const float* W1 = (const float*)d_in[3];
    const float* b1 = (const float*)d_in[4];
    const float* W2 = (const float*)d_in[5];
    const float* b2 = (const float*)d_in[6];
    const float* W3 = (const float*)d_in[7];
    const float* b3 = (const float*)d_in[8];
    const float* W4 = (const float*)d_in[9];
    const float* b4 = (const float*)d_in[10];
    const float* lw1 = (const float*)d_in[11];
    const float* lb1 = (const float*)d_in[12];
    const float* lw2 = (const float*)d_in[13];
    const float* lb2 = (const float*)d_in[14];
    float* out = (float*)d_out;

    // workspace layout (4-byte units; sizes annotated in ints); ~39 MB
    int* wsi = (int*)d_ws;
    int* gcount = wsi;                                      // @0        128
    int* gptot = wsi + 128;                                 // @128      128
    int* gpbase = wsi + 256;                                // @256      256
    int* cnt = wsi + 512;                                   // @512      50176
    int* rowptr = wsi + 50688;                              // @50688    50064 (NPAD+1)
    unsigned short* csr = (unsigned short*)(wsi + 100752);  // @100752   600000 (1.2M ushorts)
    float* dinv = (float*)(wsi + 700752);                   // @700752   50048
    unsigned short* Wt1 = (unsigned short*)(wsi + 750800);  // @750800   4096 (8192 shorts)
    unsigned short* Wt2 = (unsigned short*)(wsi + 754896);  // @754896   8192 (16384 shorts)
    unsigned short* Wt3 = (unsigned short*)(wsi + 763088);  // @763088   8192
    unsigned short* Wt4 = (unsigned short*)(wsi + 771280);  // @771280   8192
    unsigned short* xb = (unsigned short*)(wsi + 779472);   // @779472   1601536 (NPAD*64 shorts)
    unsigned int* hb = (unsigned int*)(wsi + 2381008);      // @2381008  3203072 (NPAD*64 uints)
    unsigned int* hwb = (unsigned int*)(wsi + 5584080);     // @5584080  3203072
    float* pooled = (float*)(wsi + 8787152);                // @8787152  2064 (NG*H+NG)
    float* pcnt = pooled + NG * H;
    unsigned int* ebuf = (unsigned int*)(wsi + 8789216);    // @8789216  980000 -> ends 9769216

    const int gemmBlocks = NPAD / 64;          // 782
    const int aggBlocks = 4 * AGG_CH;          // 12500, chunk-major
    const int prepBlocks = (NPAD * FIN + H * FIN + 3 * H * H + 255) / 256;

    // ---- CSR build (bucket-local; reused by all 4 layers) ----
    hipMemsetAsync(gcount, 0, NBUCK * sizeof(int), stream);
    fillA_kernel<<<FILLA_BLOCKS, 256, 0, stream>>>(ei, gcount, ebuf);
    fillB1_kernel<<<NBUCK, 256, 0, stream>>>(ebuf, gcount, cnt, gptot);
    scan98_kernel<<<1, 256, 0, stream>>>(gptot, gpbase, pooled);
    fillB2_kernel<<<NBUCK, 256, 0, stream>>>(ebuf, gcount, cnt, gpbase, rowptr, dinv, csr);

    // ---- input/weight converts (one launch) ----
    prep_kernel<<<prepBlocks, 256, 0, stream>>>(x, W1, W2, W3, W4, xb, Wt1, Wt2, Wt3, Wt4);

    // ---- layer 1 ----
    gemm_mfma_kernel<FIN><<<gemmBlocks, 256, 0, stream>>>(xb, Wt1, dinv, hwb);
    agg_kernel<true><<<aggBlocks, 256, 0, stream>>>(hwb, rowptr, csr, dinv, b1, hb);
    // ---- layer 2 ----
    gemm_mfma_kernel<H><<<gemmBlocks, 256, 0, stream>>>((unsigned short*)hb, Wt2, dinv, hwb);
    agg_kernel<true><<<aggBlocks, 256, 0, stream>>>(hwb, rowptr, csr, dinv, b2, hb);
    // ---- layer 3 ----
    gemm_mfma_kernel<H><<<gemmBlocks, 256, 0, stream>>>((unsigned short*)hb, Wt3, dinv, hwb);
    agg_kernel<true><<<aggBlocks, 256, 0, stream>>>(hwb, rowptr, csr, dinv, b3, hb);
    // ---- layer 4 (no relu/bias; b4 fused in pool) ----
    gemm_mfma_kernel<H><<<gemmBlocks, 256, 0, stream>>>((unsigned short*)hb, Wt4, dinv, hwb);
    agg_kernel<false><<<aggBlocks, 256, 0, stream>>>(hwb, rowptr, csr, dinv, nullptr, hb);

    // ---- pooling (fused +b4, pooled zeroed in scan98) + MLP ----
    pool_kernel<<<POOL_BLOCKS, 256, 0, stream>>>(hb, b4, batch, pooled, pcnt);
    mlp_kernel<<<1, 1024, 0, stream>>>(pooled, pcnt, lw1, lb1, lw2, lb2, out);
}

// Round 16
// 367.819 us; speedup vs baseline: 1.2034x; 1.0202x over previous
//
#include <hip/hip_runtime.h>

#define NN 50000
#define NPAD 50048   // rows padded to multiple of 64 for MFMA tiles
#define NE 800000
#define FIN 64
#define H 128
#define NG 16
#define POOL_BLOCKS 200
#define POOL_NODES 250
#define NBUCK 98         // buckets of 512 dst nodes
#define BUCK_CAP 10000   // edges per bucket capacity (expected 8163 +- 90)
#define FILLA_BLOCKS 512
#define FILLA_CHUNK 1563  // ceil(NE / FILLA_BLOCKS)
#define CHUNK_U 16       // uints per node per feature-chunk (32 feats)
#define DUMMY NN         // zero pad row used for CSR padding
#define AGG_CH (NN / 16) // 3125 blocks per chunk

typedef __bf16 bf16x8 __attribute__((ext_vector_type(8)));
typedef float f32x4 __attribute__((ext_vector_type(4)));

// ---- helpers ----
__device__ inline unsigned short bf16r(float x) {
    unsigned int u = __float_as_uint(x);
    return (unsigned short)((u + 0x7fffu + ((u >> 16) & 1u)) >> 16);
}
__device__ inline unsigned int pack_bf16x2(float a, float b) {
    return (unsigned int)bf16r(a) | ((unsigned int)bf16r(b) << 16);
}
__device__ inline float bf_lo(unsigned int u) { return __uint_as_float(u << 16); }
__device__ inline float bf_hi(unsigned int u) { return __uint_as_float(u & 0xffff0000u); }

// ================= CSR build (bucket-local, 2 kernels + 1 tiny memset) =================
// fillA: bucket edges by dst>>9 into fixed-capacity bucket windows of ebuf.
// Block 0 also zeroes pooled/pcnt (used much later by pool_kernel).
__global__ __launch_bounds__(256) void fillA_kernel(const int* __restrict__ ei,
                                                    int* __restrict__ gcount,
                                                    unsigned int* __restrict__ ebuf,
                                                    float* __restrict__ pooled) {
    __shared__ int hist[128];
    __shared__ int base[128];
    const int t = threadIdx.x;
    if (blockIdx.x == 0)
        for (int i = t; i < NG * H + NG; i += 256) pooled[i] = 0.f;
    if (t < 128) hist[t] = 0;
    __syncthreads();
    const int e0 = blockIdx.x * FILLA_CHUNK;
    const int e1 = min(e0 + FILLA_CHUNK, NE);
    for (int e = e0 + t; e < e1; e += 256)
        atomicAdd(&hist[ei[NE + e] >> 9], 1);
    __syncthreads();
    if (t < 128) {
        int h = (t < NBUCK) ? hist[t] : 0;
        base[t] = h ? atomicAdd(&gcount[t], h) : 0;
    }
    __syncthreads();
    for (int e = e0 + t; e < e1; e += 256) {
        int d = ei[NE + e];
        int s = ei[e];
        int b = d >> 9;
        int pos = atomicAdd(&base[b], 1);
        ebuf[b * BUCK_CAP + pos] = (unsigned int)s | ((unsigned int)d << 16);
    }
}

// fillB (fused hist+scan+scatter): per bucket: LDS hist -> padded counts ->
// local scan -> one global atomicAdd reserves the bucket's csr window ->
// rowse (start,end) + dinv + LDS-cursor scatter + DUMMY pads.
// Bucket windows are 8-aligned but NOT node-ordered across buckets (rowse
// carries both ends, so agg never relies on contiguity).
__global__ __launch_bounds__(256) void fillB_kernel(const unsigned int* __restrict__ ebuf,
                                                    const int* __restrict__ gcount,
                                                    int* __restrict__ galloc,
                                                    int2* __restrict__ rowse,
                                                    float* __restrict__ dinv,
                                                    unsigned short* __restrict__ csr) {
    __shared__ int lh[512];
    __shared__ int lsum[256];
    __shared__ int loff[512];
    __shared__ int lcur[512];
    __shared__ int base_s;
    const int b = blockIdx.x, t = threadIdx.x;
    const int n0 = b * 512;
    lh[t] = 0;
    lh[t + 256] = 0;
    __syncthreads();
    const int ne = gcount[b];
    const unsigned int* __restrict__ eb = ebuf + b * BUCK_CAP;
    for (int i = t; i < ne; i += 256)
        atomicAdd(&lh[(int)(eb[i] >> 16) - n0], 1);
    __syncthreads();
    const int c0 = lh[2 * t], c1 = lh[2 * t + 1];
    const int p0 = (c0 + 7) & ~7, p1 = (c1 + 7) & ~7;
    lsum[t] = p0 + p1;
    __syncthreads();
    for (int off = 1; off < 256; off <<= 1) {
        int u = (t >= off) ? lsum[t - off] : 0;
        __syncthreads();
        lsum[t] += u;
        __syncthreads();
    }
    if (t == 255) base_s = atomicAdd(galloc, lsum[255]);
    int excl = (t == 0) ? 0 : lsum[t - 1];
    __syncthreads();
    const int base = base_s;
    loff[2 * t] = excl;
    loff[2 * t + 1] = excl + p0;
    {
        int j = 2 * t, n = n0 + j;
        int st = base + excl;
        if (n < NN) {
            rowse[n] = make_int2(st, st + p0);
            dinv[n] = rsqrtf((float)c0 + 1.0f);  // +1 self-loop
        } else if (n < NPAD) {
            rowse[n] = make_int2(0, 0);
            dinv[n] = 0.0f;
        }
        lcur[j] = st;
        int st1 = st + p0, n1 = n + 1;
        if (n1 < NN) {
            rowse[n1] = make_int2(st1, st1 + p1);
            dinv[n1] = rsqrtf((float)c1 + 1.0f);
        } else if (n1 < NPAD) {
            rowse[n1] = make_int2(0, 0);
            dinv[n1] = 0.0f;
        }
        lcur[j + 1] = st1;
    }
    __syncthreads();
    for (int i = t; i < ne; i += 256) {
        unsigned int u = eb[i];
        int s = (int)(u & 0xFFFFu);
        int j = (int)(u >> 16) - n0;
        int pos = atomicAdd(&lcur[j], 1);
        csr[pos] = (unsigned short)s;
    }
    __syncthreads();
    {
        int j = 2 * t;
        int st = base + loff[j] + c0, en = base + loff[j] + p0;
        for (int k = st; k < en; k++) csr[k] = (unsigned short)DUMMY;
        int st1 = base + loff[j + 1] + c1, en1 = base + loff[j + 1] + p1;
        for (int k = st1; k < en1; k++) csr[k] = (unsigned short)DUMMY;
    }
}

// ================= prep: x convert (chunked) + all 4 weight transposes =================
__global__ __launch_bounds__(256) void prep_kernel(const float* __restrict__ x,
                                                   const float* __restrict__ W1,
                                                   const float* __restrict__ W2,
                                                   const float* __restrict__ W3,
                                                   const float* __restrict__ W4,
                                                   unsigned short* __restrict__ xb,
                                                   unsigned short* __restrict__ Wt1,
                                                   unsigned short* __restrict__ Wt2,
                                                   unsigned short* __restrict__ Wt3,
                                                   unsigned short* __restrict__ Wt4) {
    int e = blockIdx.x * 256 + threadIdx.x;
    if (e < NPAD * FIN) {
        int n = e >> 6, k = e & 63;
        unsigned short v = (n < NN) ? bf16r(x[n * FIN + k]) : (unsigned short)0;
        xb[(size_t)(k >> 5) * (NPAD * 32) + n * 32 + (k & 31)] = v;
        return;
    }
    int t = e - NPAD * FIN;
    if (t < H * FIN) {
        int n = t / FIN, k = t % FIN;
        Wt1[t] = bf16r(W1[k * H + n]);
        return;
    }
    int u = t - H * FIN;
    const float* W = W2;
    unsigned short* Wt = Wt2;
    if (u >= 2 * H * H) { W = W4; Wt = Wt4; u -= 2 * H * H; }
    else if (u >= H * H) { W = W3; Wt = Wt3; u -= H * H; }
    if (u < H * H) {
        int n = u / H, k = u % H;
        Wt[u] = bf16r(W[k * H + n]);
    }
}

// ===== MFMA GEMM (chunked in/out): hw' = (h @ W) * dinv[row], bf16 out =====
#define LSTRIDE 130
template <int K>
__global__ __launch_bounds__(256) void gemm_mfma_kernel(const unsigned short* __restrict__ hb,
                                                        const unsigned short* __restrict__ Wt,
                                                        const float* __restrict__ dinv,
                                                        unsigned int* __restrict__ outu) {
    __shared__ float ls[64 * LSTRIDE];  // ~33 KB
    const int wave = threadIdx.x >> 6, lane = threadIdx.x & 63;
    const int m15 = lane & 15, quad = lane >> 4;
    const int row0 = blockIdx.x * 64;
    const int arow = row0 + wave * 16 + m15;

    bf16x8 a[K / 32];
#pragma unroll
    for (int ks = 0; ks < K / 32; ks++)
        a[ks] = *(const bf16x8*)&hb[(size_t)ks * (NPAD * 32) + arow * 32 + quad * 8];

    const int lrow = wave * 16 + quad * 4;
    float dv[4];
#pragma unroll
    for (int r = 0; r < 4; r++) dv[r] = dinv[row0 + lrow + r];

#pragma unroll
    for (int ct = 0; ct < 8; ct++) {
        f32x4 acc = {0.f, 0.f, 0.f, 0.f};
#pragma unroll
        for (int ks = 0; ks < K / 32; ks++) {
            bf16x8 b = *(const bf16x8*)&Wt[(ct * 16 + m15) * K + ks * 32 + quad * 8];
            acc = __builtin_amdgcn_mfma_f32_16x16x32_bf16(a[ks], b, acc, 0, 0, 0);
        }
#pragma unroll
        for (int r = 0; r < 4; r++)
            ls[(lrow + r) * LSTRIDE + ct * 16 + m15] = acc[r] * dv[r];
    }
    __syncthreads();

#pragma unroll
    for (int k = 0; k < 4; k++) {
        int idx = threadIdx.x + 256 * k;
        int c = idx >> 8, row = (idx >> 2) & 63, q = idx & 3;
        const float* p = &ls[row * LSTRIDE + c * 32 + q * 8];
        uint4 o;
        o.x = pack_bf16x2(p[0], p[1]);
        o.y = pack_bf16x2(p[2], p[3]);
        o.z = pack_bf16x2(p[4], p[5]);
        o.w = pack_bf16x2(p[6], p[7]);
        *(uint4*)&outu[(size_t)c * (NPAD * CHUNK_U) + (size_t)(row0 + row) * CHUNK_U + q * 4] = o;
    }
}

// ====== feature-chunked gather aggregation, one node per 16-lane group ======
template <bool RELU_BIAS>
__global__ __launch_bounds__(256) void agg_kernel(const unsigned int* __restrict__ hwc,
                                                  const int2* __restrict__ rowse,
                                                  const unsigned short* __restrict__ csr,
                                                  const float* __restrict__ dinv,
                                                  const float* __restrict__ bias,
                                                  unsigned int* __restrict__ outc) {
    const int chunk = blockIdx.x / AGG_CH;
    const int nb = blockIdx.x % AGG_CH;
    const int wave = threadIdx.x >> 6, lane = threadIdx.x & 63;
    const int g = lane >> 4, u = lane & 15;
    const int n = nb * 16 + wave * 4 + g;
    const unsigned int* __restrict__ slice = hwc + (size_t)chunk * (NPAD * CHUNK_U);

    unsigned int sv = slice[n * CHUNK_U + u];  // self-loop term
    float ax = bf_lo(sv), ay = bf_hi(sv);

    const int2 se = rowse[n];  // start/end, both multiples of 8
    for (int i = se.x; i < se.y; i += 8) {
        uint4 c = *(const uint4*)&csr[i];  // 8 ushort srcs
        int s0 = c.x & 0xFFFF, s1 = c.x >> 16;
        int s2 = c.y & 0xFFFF, s3 = c.y >> 16;
        int s4 = c.z & 0xFFFF, s5 = c.z >> 16;
        int s6 = c.w & 0xFFFF, s7 = c.w >> 16;
        unsigned int v0 = slice[s0 * CHUNK_U + u], v1 = slice[s1 * CHUNK_U + u];
        unsigned int v2 = slice[s2 * CHUNK_U + u], v3 = slice[s3 * CHUNK_U + u];
        unsigned int v4 = slice[s4 * CHUNK_U + u], v5 = slice[s5 * CHUNK_U + u];
        unsigned int v6 = slice[s6 * CHUNK_U + u], v7 = slice[s7 * CHUNK_U + u];
        ax += bf_lo(v0) + bf_lo(v1) + bf_lo(v2) + bf_lo(v3) +
              bf_lo(v4) + bf_lo(v5) + bf_lo(v6) + bf_lo(v7);
        ay += bf_hi(v0) + bf_hi(v1) + bf_hi(v2) + bf_hi(v3) +
              bf_hi(v4) + bf_hi(v5) + bf_hi(v6) + bf_hi(v7);
    }

    float d = dinv[n];
    ax *= d;
    ay *= d;
    if (RELU_BIAS) {
        float2 bv = ((const float2*)bias)[chunk * CHUNK_U + u];
        ax = fmaxf(ax + bv.x, 0.f);
        ay = fmaxf(ay + bv.y, 0.f);
    }
    outc[(size_t)chunk * (NPAD * CHUNK_U) + n * CHUNK_U + u] = pack_bf16x2(ax, ay);
}

// ======== pooling: block-local segment reduction (batch sorted), chunked bf16 in ========
__global__ __launch_bounds__(256) void pool_kernel(const unsigned int* __restrict__ hbu,
                                                   const float* __restrict__ b4,
                                                   const int* __restrict__ batch,
                                                   float* __restrict__ pooled,
                                                   float* __restrict__ cnt) {
    __shared__ int bs[POOL_NODES];
    const int tid = threadIdx.x;
    const int n0 = blockIdx.x * POOL_NODES;
    for (int i = tid; i < POOL_NODES; i += 256) bs[i] = batch[n0 + i];
    __syncthreads();
    const int c2 = tid & 63;                 // feature-uint index 0..63
    const int chunk = c2 >> 4, u = c2 & 15;
    const int rsub = tid >> 6;  // 0..3
    float2 bb = ((const float2*)b4)[c2];
    float2 acc = {0.f, 0.f};
    float cacc = 0.f;
    int curg = bs[rsub];
    const size_t coff = (size_t)chunk * (NPAD * CHUNK_U) + u;
    for (int r = rsub; r < POOL_NODES; r += 4) {
        int g = bs[r];
        if (g != curg) {
            atomicAdd(&pooled[curg * H + c2 * 2], acc.x);
            atomicAdd(&pooled[curg * H + c2 * 2 + 1], acc.y);
            if (c2 == 0) atomicAdd(&cnt[curg], cacc);
            acc.x = acc.y = 0.f;
            cacc = 0.f;
            curg = g;
        }
        unsigned int v = hbu[coff + (size_t)(n0 + r) * CHUNK_U];
        acc.x += bf_lo(v) + bb.x;
        acc.y += bf_hi(v) + bb.y;
        cacc += 1.f;
    }
    atomicAdd(&pooled[curg * H + c2 * 2], acc.x);
    atomicAdd(&pooled[curg * H + c2 * 2 + 1], acc.y);
    if (c2 == 0) atomicAdd(&cnt[curg], cacc);
}

// ================= final MLP (single block) =================
__global__ __launch_bounds__(1024) void mlp_kernel(const float* __restrict__ pooled,
                                                   const float* __restrict__ cnt,
                                                   const float* __restrict__ lw1,
                                                   const float* __restrict__ lb1,
                                                   const float* __restrict__ lw2,
                                                   const float* __restrict__ lb2,
                                                   float* __restrict__ out) {
    __shared__ float mean_s[NG * H];
    __shared__ float hid_s[NG * 64];
    int tid = threadIdx.x;
    for (int i = tid; i < NG * H; i += 1024) {
        int g = i >> 7;
        mean_s[i] = pooled[i] / fmaxf(cnt[g], 1.0f);
    }
    __syncthreads();
    {
        int g = tid >> 6, j = tid & 63;
        float acc = lb1[j];
        for (int f = 0; f < H; f++) acc += mean_s[g * H + f] * lw1[f * 64 + j];
        hid_s[g * 64 + j] = fmaxf(acc, 0.f);
    }
    __syncthreads();
    if (tid < 32) {
        int g = tid >> 1, c = tid & 1;
        float acc = lb2[c];
        for (int j = 0; j < 64; j++) acc += hid_s[g * 64 + j] * lw2[j * 2 + c];
        out[g * 2 + c] = acc;
    }
}

extern "C" void kernel_launch(void* const* d_in, const int* in_sizes, int n_in,
                              void* d_out, int out_size, void* d_ws, size_t ws_size,
                              hipStream_t stream) {
    const float* x = (const float*)d_in[0];
    const int* ei = (const int*)d_in[1];
    const int* batch = (const int*)d_in[2];
    const float* W1 = (const float*)d_in[3];
    const float* b1 = (const float*)d_in[4];
    const float* W2 = (const float*)d_in[5];
    const float* b2 = (const float*)d_in[6];
    const float* W3 = (const float*)d_in[7];
    const float* b3 = (const float*)d_in[8];
    const float* W4 = (const float*)d_in[9];
    const float* b4 = (const float*)d_in[10];
    const float* lw1 = (const float*)d_in[11];
    const float* lb1 = (const float*)d_in[12];
    const float* lw2 = (const float*)d_in[13];
    const float* lb2 = (const float*)d_in[14];
    float* out = (float*)d_out;

    // workspace layout (4-byte units; sizes annotated in ints); ~39 MB
    int* wsi = (int*)d_ws;
    int* gcount = wsi;                                      // @0        128
    int* galloc = wsi + 128;                                // @128      (memset covers both)
    int2* rowse = (int2*)(wsi + 512);                       // @512      100096 (NPAD int2)
    unsigned short* csr = (unsigned short*)(wsi + 100608);  // @100608   600000 (1.2M ushorts)
    float* dinv = (float*)(wsi + 700608);                   // @700608   50048
    unsigned short* Wt1 = (unsigned short*)(wsi + 750656);  // @750656   4096 (8192 shorts)
    unsigned short* Wt2 = (unsigned short*)(wsi + 754752);  // @754752   8192 (16384 shorts)
    unsigned short* Wt3 = (unsigned short*)(wsi + 762944);  // @762944   8192
    unsigned short* Wt4 = (unsigned short*)(wsi + 771136);  // @771136   8192
    unsigned short* xb = (unsigned short*)(wsi + 779328);   // @779328   1601536 (NPAD*64 shorts)
    unsigned int* hb = (unsigned int*)(wsi + 2380864);      // @2380864  3203072 (NPAD*64 uints)
    unsigned int* hwb = (unsigned int*)(wsi + 5583936);     // @5583936  3203072
    float* pooled = (float*)(wsi + 8787008);                // @8787008  2064 (NG*H+NG)
    float* pcnt = pooled + NG * H;
    unsigned int* ebuf = (unsigned int*)(wsi + 8789072);    // @8789072  980000 -> ends 9769072

    const int gemmBlocks = NPAD / 64;          // 782
    const int aggBlocks = 4 * AGG_CH;          // 12500, chunk-major
    const int prepBlocks = (NPAD * FIN + H * FIN + 3 * H * H + 255) / 256;

    // ---- CSR build (bucket-local; reused by all 4 layers) ----
    hipMemsetAsync(gcount, 0, 256 * sizeof(int), stream);  // gcount + galloc
    fillA_kernel<<<FILLA_BLOCKS, 256, 0, stream>>>(ei, gcount, ebuf, pooled);
    fillB_kernel<<<NBUCK, 256, 0, stream>>>(ebuf, gcount, galloc, rowse, dinv, csr);

    // ---- input/weight converts (one launch) ----
    prep_kernel<<<prepBlocks, 256, 0, stream>>>(x, W1, W2, W3, W4, xb, Wt1, Wt2, Wt3, Wt4);

    // ---- layer 1 ----
    gemm_mfma_kernel<FIN><<<gemmBlocks, 256, 0, stream>>>(xb, Wt1, dinv, hwb);
    agg_kernel<true><<<aggBlocks, 256, 0, stream>>>(hwb, rowse, csr, dinv, b1, hb);
    // ---- layer 2 ----
    gemm_mfma_kernel<H><<<gemmBlocks, 256, 0, stream>>>((unsigned short*)hb, Wt2, dinv, hwb);
    agg_kernel<true><<<aggBlocks, 256, 0, stream>>>(hwb, rowse, csr, dinv, b2, hb);
    // ---- layer 3 ----
    gemm_mfma_kernel<H><<<gemmBlocks, 256, 0, stream>>>((unsigned short*)hb, Wt3, dinv, hwb);
    agg_kernel<true><<<aggBlocks, 256, 0, stream>>>(hwb, rowse, csr, dinv, b3, hb);
    // ---- layer 4 (no relu/bias; b4 fused in pool) ----
    gemm_mfma_kernel<H><<<gemmBlocks, 256, 0, stream>>>((unsigned short*)hb, Wt4, dinv, hwb);
    agg_kernel<false><<<aggBlocks, 256, 0, stream>>>(hwb, rowse, csr, dinv, nullptr, hb);

    // ---- pooling (fused +b4, pooled zeroed in fillA) + MLP ----
    pool_kernel<<<POOL_BLOCKS, 256, 0, stream>>>(hb, b4, batch, pooled, pcnt);
    mlp_kernel<<<1, 1024, 0, stream>>>(pooled, pcnt, lw1, lb1, lw2, lb2, out);
}